// Round 2
// baseline (1459.310 us; speedup 1.0000x reference)
//
#include <hip/hip_runtime.h>
#include <hip/hip_bf16.h>
#include <math.h>

#define DD 128
#define EPS 1e-5f

// ---------------- preprocessing ----------------

__global__ __launch_bounds__(256) void init_deg(int* deg, int n) {
    int i = blockIdx.x * 256 + threadIdx.x;
    if (i < n) deg[i] = 1;  // self loop
}

// NOTE: harness delivers integer inputs as int32 (contract: "integer -> const int*")
__global__ __launch_bounds__(256) void count_deg(const int* __restrict__ ei, int* deg, int ne) {
    int e = blockIdx.x * 256 + threadIdx.x;
    if (e < ne) atomicAdd(&deg[ei[ne + e]], 1);  // col = target
}

__global__ __launch_bounds__(256) void dis_kernel(const int* __restrict__ deg, float* dis, int n) {
    int i = blockIdx.x * 256 + threadIdx.x;
    if (i < n) dis[i] = rsqrtf((float)deg[i]);
}

// single-block exclusive scan of (deg[i]-1) -> offs, cursor
__global__ __launch_bounds__(1024) void scan_offsets(const int* __restrict__ deg, int* offs, int* cursor, int n) {
    __shared__ int part[1024];
    int t = threadIdx.x;
    int chunk = (n + 1023) / 1024;
    int s0 = t * chunk;
    int s1 = min(n, s0 + chunk);
    int local = 0;
    for (int i = s0; i < s1; i++) local += deg[i] - 1;
    part[t] = local;
    __syncthreads();
    for (int off = 1; off < 1024; off <<= 1) {
        int v = part[t];
        int add = (t >= off) ? part[t - off] : 0;
        __syncthreads();
        part[t] = v + add;
        __syncthreads();
    }
    int base = (t == 0) ? 0 : part[t - 1];
    for (int i = s0; i < s1; i++) {
        offs[i] = base;
        cursor[i] = base;
        base += deg[i] - 1;
    }
    if (t == 1023) offs[n] = part[1023];
}

__global__ __launch_bounds__(256) void fill_edges(const int* __restrict__ ei, int* cursor, int* ebuf, int ne) {
    int e = blockIdx.x * 256 + threadIdx.x;
    if (e >= ne) return;
    int r = ei[e];        // source
    int c = ei[ne + e];   // target
    int pos = atomicAdd(&cursor[c], 1);
    ebuf[pos] = r;
}

// u[i][d] = sum_j skip_w[i][d][j] * readout_w[i*D + j]
__global__ void compute_u(const float* __restrict__ skip_w, const float* __restrict__ readout_w, float* u) {
    int i = blockIdx.x;   // 0..3
    int d = threadIdx.x;  // 0..127
    float s = 0.f;
    const float* sw = skip_w + i * DD * DD + d * DD;
    const float* rw = readout_w + i * DD;
    for (int j = 0; j < DD; j++) s += sw[j] * rw[j];
    u[i * DD + d] = s;
}

// ---------------- GEMM: Y[i][j] = bias[j] + sum_k X[i][k] * W[k][j] ----------------
__global__ __launch_bounds__(256) void gemm_xw(const float* __restrict__ X, const float* __restrict__ Wg,
                                               const float* __restrict__ bias, float* __restrict__ Y, int nrows) {
    __shared__ float Xs[32][DD + 1];
    __shared__ float Ws[64][DD];
    int t = threadIdx.x;
    int row0 = blockIdx.x * 32;
    int nr = min(32, nrows - row0);
    for (int i = t; i < 32 * 32; i += 256) {
        int r = i >> 5, c4 = i & 31;
        float4 v = make_float4(0.f, 0.f, 0.f, 0.f);
        if (r < nr) v = *(const float4*)(X + (size_t)(row0 + r) * DD + c4 * 4);
        Xs[r][c4 * 4 + 0] = v.x; Xs[r][c4 * 4 + 1] = v.y;
        Xs[r][c4 * 4 + 2] = v.z; Xs[r][c4 * 4 + 3] = v.w;
    }
    int r  = t >> 3;        // 0..31
    int cg = t & 7;         // col group; thread owns cols cg*4 + q*32, q=0..3
    float acc[4][4];
    #pragma unroll
    for (int q = 0; q < 4; q++)
        #pragma unroll
        for (int j = 0; j < 4; j++) acc[q][j] = 0.f;

    for (int kc = 0; kc < 2; kc++) {
        __syncthreads();
        for (int i = t; i < 64 * 32; i += 256) {
            int kk = i >> 5, c4 = i & 31;
            *(float4*)&Ws[kk][c4 * 4] = *(const float4*)(Wg + (size_t)(kc * 64 + kk) * DD + c4 * 4);
        }
        __syncthreads();
        #pragma unroll 8
        for (int k = 0; k < 64; k++) {
            float xv = Xs[r][kc * 64 + k];
            #pragma unroll
            for (int q = 0; q < 4; q++) {
                float4 w = *(const float4*)&Ws[k][cg * 4 + q * 32];
                acc[q][0] += xv * w.x; acc[q][1] += xv * w.y;
                acc[q][2] += xv * w.z; acc[q][3] += xv * w.w;
            }
        }
    }
    int row = row0 + r;
    if (row < nrows) {
        float* y = Y + (size_t)row * DD;
        #pragma unroll
        for (int q = 0; q < 4; q++) {
            int j = cg * 4 + q * 32;
            float4 o;
            o.x = acc[q][0]; o.y = acc[q][1]; o.z = acc[q][2]; o.w = acc[q][3];
            if (bias) { o.x += bias[j]; o.y += bias[j + 1]; o.z += bias[j + 2]; o.w += bias[j + 3]; }
            *(float4*)(y + j) = o;
        }
    }
}

// ---------------- aggregation: one wave per node ----------------
// agg[v] = dis[v] * ( sum_{e: col=v} dis[src]*hl[src] + dis[v]*hl[v] )
__global__ __launch_bounds__(256) void aggregate(const float* __restrict__ hl, const int* __restrict__ ebuf,
                                                 const int* __restrict__ offs, const float* __restrict__ dis,
                                                 float* __restrict__ agg, int n) {
    int w = threadIdx.x >> 6;
    int lane = threadIdx.x & 63;
    int v = blockIdx.x * 4 + w;
    if (v >= n) return;
    float dv = dis[v];
    float2 acc = ((const float2*)(hl + (size_t)v * DD))[lane];
    acc.x *= dv; acc.y *= dv;
    int e0 = offs[v], e1 = offs[v + 1];
    int src_next = (e0 < e1) ? ebuf[e0] : 0;
    for (int e = e0; e < e1; e++) {
        int src = src_next;
        if (e + 1 < e1) src_next = ebuf[e + 1];
        float s = dis[src];
        float2 m = ((const float2*)(hl + (size_t)src * DD))[lane];
        acc.x += s * m.x; acc.y += s * m.y;
    }
    float2 o; o.x = acc.x * dv; o.y = acc.y * dv;
    ((float2*)(agg + (size_t)v * DD))[lane] = o;
}

// ---------------- batchnorm ----------------

__global__ void zero_stats(float* stats) { stats[threadIdx.x] = 0.f; }

__global__ __launch_bounds__(256) void bn_stats(const float* __restrict__ agg, float* stats, int n) {
    int d = threadIdx.x & 127;
    int rg = threadIdx.x >> 7;  // 0..1
    float s = 0.f, s2 = 0.f;
    for (int i = blockIdx.x * 2 + rg; i < n; i += gridDim.x * 2) {
        float v = agg[(size_t)i * DD + d];
        s += v; s2 += v * v;
    }
    __shared__ float ls[2][DD], ls2[2][DD];
    ls[rg][d] = s; ls2[rg][d] = s2;
    __syncthreads();
    if (rg == 0) {
        atomicAdd(&stats[d], ls[0][d] + ls[1][d]);
        atomicAdd(&stats[d + DD], ls2[0][d] + ls2[1][d]);
    }
}

// BN + relu + write feats (in-place safe) + logits += f . u
__global__ __launch_bounds__(256) void bn_apply(const float* __restrict__ agg, const float* __restrict__ stats,
                                                const float* __restrict__ g, const float* __restrict__ b,
                                                const float* __restrict__ u, float* __restrict__ fout,
                                                float* __restrict__ logits, int n, float invN) {
    int d = threadIdx.x & 127;
    int which = threadIdx.x >> 7;       // node within block
    int i = blockIdx.x * 2 + which;
    __shared__ float red[2][2];
    float c = 0.f;
    if (i < n) {
        float mean = stats[d] * invN;
        float ex2 = stats[d + DD] * invN;
        float var = ex2 - mean * mean;
        float f = (agg[(size_t)i * DD + d] - mean) * rsqrtf(var + EPS) * g[d] + b[d];
        f = fmaxf(f, 0.f);
        fout[(size_t)i * DD + d] = f;
        c = f * u[d];
    }
    #pragma unroll
    for (int off = 32; off; off >>= 1) c += __shfl_down(c, off);
    int lane = threadIdx.x & 63;
    int wv = (threadIdx.x >> 6) & 1;
    if (lane == 0) red[which][wv] = c;
    __syncthreads();
    if (i < n && (threadIdx.x & 127) == 0) logits[i] += red[which][0] + red[which][1];
}

// logits[i] = h[i] . u0
__global__ __launch_bounds__(256) void dot_init(const float* __restrict__ h, const float* __restrict__ u,
                                                float* __restrict__ logits, int n) {
    int d = threadIdx.x & 127;
    int which = threadIdx.x >> 7;
    int i = blockIdx.x * 2 + which;
    __shared__ float red[2][2];
    float c = 0.f;
    if (i < n) c = h[(size_t)i * DD + d] * u[d];
    #pragma unroll
    for (int off = 32; off; off >>= 1) c += __shfl_down(c, off);
    int lane = threadIdx.x & 63;
    int wv = (threadIdx.x >> 6) & 1;
    if (lane == 0) red[which][wv] = c;
    __syncthreads();
    if (i < n && (threadIdx.x & 127) == 0) logits[i] = red[which][0] + red[which][1];
}

__global__ __launch_bounds__(256) void finalize(const float* __restrict__ logits, float* __restrict__ out, int n) {
    int i = blockIdx.x * 256 + threadIdx.x;
    if (i < n) {
        float x = logits[i];
        out[i] = x;
        out[n + i] = 1.f / (1.f + expf(-x));
    }
}

// ---------------- host ----------------

static inline size_t align_up(size_t x, size_t a) { return (x + a - 1) & ~(a - 1); }

extern "C" void kernel_launch(void* const* d_in, const int* in_sizes, int n_in,
                              void* d_out, int out_size, void* d_ws, size_t ws_size,
                              hipStream_t stream) {
    const float* x       = (const float*)d_in[0];
    const int*   ei      = (const int*)d_in[1];      // int32 per harness contract
    const float* emb_w   = (const float*)d_in[2];
    const float* emb_b   = (const float*)d_in[3];
    const float* gcn_w   = (const float*)d_in[4];
    // d_in[5] = gcn_b: no-op (constant shift immediately normalized away by BatchNorm)
    const float* bn_g    = (const float*)d_in[6];
    const float* bn_b    = (const float*)d_in[7];
    const float* skip_w  = (const float*)d_in[8];
    const float* readout = (const float*)d_in[9];
    float* out = (float*)d_out;

    const int N = in_sizes[0] / DD;
    const int E = in_sizes[1] / 2;

    // workspace layout (~111 MB total)
    char* p = (char*)d_ws;
    size_t off = 0;
    auto alloc = [&](size_t bytes) { void* r = p + off; off = align_up(off + bytes, 256); return r; };
    int*   deg    = (int*)  alloc((size_t)N * 4);
    float* dis    = (float*)alloc((size_t)N * 4);
    int*   offs   = (int*)  alloc((size_t)(N + 1) * 4);
    int*   cursor = (int*)  alloc((size_t)N * 4);
    int*   ebuf   = (int*)  alloc((size_t)E * 4);
    float* u      = (float*)alloc(4 * DD * 4);
    float* stats  = (float*)alloc(2 * DD * 4);
    float* logits = (float*)alloc((size_t)N * 4);
    float* buf0   = (float*)alloc((size_t)N * DD * 4);  // feats / agg (ping)
    float* buf1   = (float*)alloc((size_t)N * DD * 4);  // hl (pong)
    (void)ws_size;

    int gN = (N + 255) / 256;
    int gE = (E + 255) / 256;

    // CSR build + norm
    init_deg<<<gN, 256, 0, stream>>>(deg, N);
    count_deg<<<gE, 256, 0, stream>>>(ei, deg, E);
    dis_kernel<<<gN, 256, 0, stream>>>(deg, dis, N);
    scan_offsets<<<1, 1024, 0, stream>>>(deg, offs, cursor, N);
    fill_edges<<<gE, 256, 0, stream>>>(ei, cursor, ebuf, E);
    compute_u<<<4, DD, 0, stream>>>(skip_w, readout, u);

    // embedding: h = x @ emb_w + emb_b  -> buf0
    gemm_xw<<<(N + 31) / 32, 256, 0, stream>>>(x, emb_w, emb_b, buf0, N);
    // logits = h . u0
    dot_init<<<(N + 1) / 2, 256, 0, stream>>>(buf0, u, logits, N);

    for (int l = 0; l < 3; l++) {  // layer 3's output is dead (skip uses feats[0..3])
        gemm_xw<<<(N + 31) / 32, 256, 0, stream>>>(buf0, gcn_w + (size_t)l * DD * DD, nullptr, buf1, N);
        aggregate<<<(N + 3) / 4, 256, 0, stream>>>(buf1, ebuf, offs, dis, buf0, N);
        zero_stats<<<1, 2 * DD, 0, stream>>>(stats);
        bn_stats<<<256, 256, 0, stream>>>(buf0, stats, N);
        bn_apply<<<(N + 1) / 2, 256, 0, stream>>>(buf0, stats, bn_g + l * DD, bn_b + l * DD,
                                                  u + (l + 1) * DD, buf0, logits, N, 1.0f / N);
    }
    finalize<<<gN, 256, 0, stream>>>(logits, out, N);
}

// Round 3
// 1114.850 us; speedup vs baseline: 1.3090x; 1.3090x over previous
//
#include <hip/hip_runtime.h>
#include <hip/hip_bf16.h>
#include <math.h>

#define DD 128
#define EPS 1e-5f
#define NB 256     // scan blocks
#define GS 36      // Xs LDS row stride (words): rows Δ16 -> bank Δ(16*36)%32=0 pairs only (2-way, free)

// ---------------- preprocessing ----------------

__global__ __launch_bounds__(256) void init_deg(int* deg, int n) {
    int i = blockIdx.x * 256 + threadIdx.x;
    if (i < n) deg[i] = 1;  // self loop
}

__global__ __launch_bounds__(256) void count_deg(const int* __restrict__ ei, int* deg, int ne) {
    int e = blockIdx.x * 256 + threadIdx.x;
    if (e < ne) atomicAdd(&deg[ei[ne + e]], 1);  // col = target
}

__global__ __launch_bounds__(256) void dis_kernel(const int* __restrict__ deg, float* dis, int n) {
    int i = blockIdx.x * 256 + threadIdx.x;
    if (i < n) dis[i] = rsqrtf((float)deg[i]);
}

// ---- parallel exclusive scan of (deg[i]-1), 3 kernels ----
// s1: per-block sums
__global__ __launch_bounds__(256) void scan1(const int* __restrict__ deg, int* bsum, int n) {
    int b = blockIdx.x;
    int span = (n + NB - 1) / NB;
    int s0 = b * span, s1 = min(n, s0 + span);
    int tc = (span + 255) / 256;
    int t0 = s0 + threadIdx.x * tc, t1 = min(s1, t0 + tc);
    int local = 0;
    for (int i = t0; i < t1; i++) local += deg[i] - 1;
    __shared__ int sm[256];
    sm[threadIdx.x] = local;
    __syncthreads();
    for (int off = 128; off; off >>= 1) {
        if (threadIdx.x < off) sm[threadIdx.x] += sm[threadIdx.x + off];
        __syncthreads();
    }
    if (threadIdx.x == 0) bsum[b] = sm[0];
}

// s2: single-block exclusive scan of bsum[NB]; offs[n] = total
__global__ __launch_bounds__(NB) void scan2(int* bsum, int* offs, int n) {
    __shared__ int sm[NB];
    int t = threadIdx.x;
    sm[t] = bsum[t];
    __syncthreads();
    for (int off = 1; off < NB; off <<= 1) {
        int v = sm[t];
        int add = (t >= off) ? sm[t - off] : 0;
        __syncthreads();
        sm[t] = v + add;
        __syncthreads();
    }
    bsum[t] = (t == 0) ? 0 : sm[t - 1];
    if (t == NB - 1) offs[n] = sm[NB - 1];
}

// s3: recompute local sums, block scan, write offs/cursor runs
__global__ __launch_bounds__(256) void scan3(const int* __restrict__ deg, const int* __restrict__ bsum,
                                             int* offs, int* cursor, int n) {
    int b = blockIdx.x;
    int span = (n + NB - 1) / NB;
    int s0 = b * span, s1 = min(n, s0 + span);
    int tc = (span + 255) / 256;
    int t0 = s0 + threadIdx.x * tc, t1 = min(s1, t0 + tc);
    int local = 0;
    for (int i = t0; i < t1; i++) local += deg[i] - 1;
    __shared__ int sm[256];
    int t = threadIdx.x;
    sm[t] = local;
    __syncthreads();
    for (int off = 1; off < 256; off <<= 1) {
        int v = sm[t];
        int add = (t >= off) ? sm[t - off] : 0;
        __syncthreads();
        sm[t] = v + add;
        __syncthreads();
    }
    int base = bsum[b] + ((t == 0) ? 0 : sm[t - 1]);
    for (int i = t0; i < t1; i++) {
        offs[i] = base;
        cursor[i] = base;
        base += deg[i] - 1;
    }
}

__global__ __launch_bounds__(256) void fill_edges(const int* __restrict__ ei, int* cursor, int* ebuf, int ne) {
    int e = blockIdx.x * 256 + threadIdx.x;
    if (e >= ne) return;
    int r = ei[e];        // source
    int c = ei[ne + e];   // target
    int pos = atomicAdd(&cursor[c], 1);
    ebuf[pos] = r;
}

// u[i][d] = sum_j skip_w[i][d][j] * readout_w[i*D + j]
__global__ void compute_u(const float* __restrict__ skip_w, const float* __restrict__ readout_w, float* u) {
    int i = blockIdx.x;
    int d = threadIdx.x;
    float s = 0.f;
    const float* sw = skip_w + i * DD * DD + d * DD;
    const float* rw = readout_w + i * DD;
    for (int j = 0; j < DD; j++) s += sw[j] * rw[j];
    u[i * DD + d] = s;
}

// ---------------- GEMM: Y[i][:] = ((X[i][:] @ W) + bias) * scale[i] ----------------
// BM=128, BK=32, 256 threads, 8x8 micro-tile/thread. rg=t&15 (rows i*16+rg), cg=t>>4.
__global__ __launch_bounds__(256) void gemm128(const float* __restrict__ X, const float* __restrict__ Wg,
                                               const float* __restrict__ bias, const float* __restrict__ scale,
                                               float* __restrict__ Y, int nrows) {
    __shared__ float Xs[128 * GS];   // 18.4 KB
    __shared__ float Ws[32 * DD];    // 16 KB
    int t = threadIdx.x;
    int rg = t & 15, cg = t >> 4;
    int row0 = blockIdx.x * 128;
    float acc[8][8];
    #pragma unroll
    for (int i = 0; i < 8; i++)
        #pragma unroll
        for (int j = 0; j < 8; j++) acc[i][j] = 0.f;

    for (int kc = 0; kc < 4; kc++) {
        __syncthreads();
        #pragma unroll
        for (int p = 0; p < 4; p++) {
            int i = t + p * 256;
            int r = i >> 3, f4 = i & 7;
            int grow = row0 + r;
            float4 v = make_float4(0.f, 0.f, 0.f, 0.f);
            if (grow < nrows) v = *(const float4*)(X + (size_t)grow * DD + kc * 32 + f4 * 4);
            *(float4*)&Xs[r * GS + f4 * 4] = v;
        }
        #pragma unroll
        for (int p = 0; p < 4; p++) {
            int i = t + p * 256;
            int kk = i >> 5, f4 = i & 31;
            *(float4*)&Ws[kk * DD + f4 * 4] = *(const float4*)(Wg + (size_t)(kc * 32 + kk) * DD + f4 * 4);
        }
        __syncthreads();
        #pragma unroll
        for (int kk = 0; kk < 32; kk += 4) {
            float4 xv[8];
            #pragma unroll
            for (int i = 0; i < 8; i++) xv[i] = *(const float4*)&Xs[(rg + 16 * i) * GS + kk];
            #pragma unroll
            for (int kq = 0; kq < 4; kq++) {
                float4 w0 = *(const float4*)&Ws[(kk + kq) * DD + cg * 8];
                float4 w1 = *(const float4*)&Ws[(kk + kq) * DD + cg * 8 + 4];
                #pragma unroll
                for (int i = 0; i < 8; i++) {
                    float xk = (kq == 0) ? xv[i].x : (kq == 1) ? xv[i].y : (kq == 2) ? xv[i].z : xv[i].w;
                    acc[i][0] += xk * w0.x; acc[i][1] += xk * w0.y;
                    acc[i][2] += xk * w0.z; acc[i][3] += xk * w0.w;
                    acc[i][4] += xk * w1.x; acc[i][5] += xk * w1.y;
                    acc[i][6] += xk * w1.z; acc[i][7] += xk * w1.w;
                }
            }
        }
    }
    #pragma unroll
    for (int i = 0; i < 8; i++) {
        int row = row0 + rg + 16 * i;
        if (row < nrows) {
            float s = scale ? scale[row] : 1.f;
            float4 o0, o1;
            o0.x = acc[i][0]; o0.y = acc[i][1]; o0.z = acc[i][2]; o0.w = acc[i][3];
            o1.x = acc[i][4]; o1.y = acc[i][5]; o1.z = acc[i][6]; o1.w = acc[i][7];
            if (bias) {
                int j = cg * 8;
                o0.x += bias[j];     o0.y += bias[j + 1]; o0.z += bias[j + 2]; o0.w += bias[j + 3];
                o1.x += bias[j + 4]; o1.y += bias[j + 5]; o1.z += bias[j + 6]; o1.w += bias[j + 7];
            }
            o0.x *= s; o0.y *= s; o0.z *= s; o0.w *= s;
            o1.x *= s; o1.y *= s; o1.z *= s; o1.w *= s;
            float* y = Y + (size_t)row * DD + cg * 8;
            *(float4*)y = o0;
            *(float4*)(y + 4) = o1;
        }
    }
}

// ---------------- aggregation: one wave per node ----------------
// hl2 already carries dis[src]: agg[v] = dis[v] * ( hl2[v] + sum_{e: col=v} hl2[src] )
__global__ __launch_bounds__(256) void aggregate(const float* __restrict__ hl2, const int* __restrict__ ebuf,
                                                 const int* __restrict__ offs, const float* __restrict__ dis,
                                                 float* __restrict__ agg, int n) {
    int w = threadIdx.x >> 6;
    int lane = threadIdx.x & 63;
    int v = blockIdx.x * 4 + w;
    if (v >= n) return;
    float2 acc = ((const float2*)(hl2 + (size_t)v * DD))[lane];
    int e0 = offs[v], e1 = offs[v + 1];
    int src_next = (e0 < e1) ? ebuf[e0] : 0;
    for (int e = e0; e < e1; e++) {
        int src = src_next;
        if (e + 1 < e1) src_next = ebuf[e + 1];
        float2 m = ((const float2*)(hl2 + (size_t)src * DD))[lane];
        acc.x += m.x; acc.y += m.y;
    }
    float dv = dis[v];
    float2 o; o.x = acc.x * dv; o.y = acc.y * dv;
    ((float2*)(agg + (size_t)v * DD))[lane] = o;
}

// ---------------- batchnorm ----------------

__global__ void zero_stats(float* stats) { stats[threadIdx.x] = 0.f; }

__global__ __launch_bounds__(256) void bn_stats(const float* __restrict__ agg, float* stats, int n) {
    int d = threadIdx.x & 127;
    int rg = threadIdx.x >> 7;
    float s = 0.f, s2 = 0.f;
    for (int i = blockIdx.x * 2 + rg; i < n; i += gridDim.x * 2) {
        float v = agg[(size_t)i * DD + d];
        s += v; s2 += v * v;
    }
    __shared__ float ls[2][DD], ls2[2][DD];
    ls[rg][d] = s; ls2[rg][d] = s2;
    __syncthreads();
    if (rg == 0) {
        atomicAdd(&stats[d], ls[0][d] + ls[1][d]);
        atomicAdd(&stats[d + DD], ls2[0][d] + ls2[1][d]);
    }
}

// BN + relu + write feats (in-place safe) + logits += f . u
__global__ __launch_bounds__(256) void bn_apply(const float* __restrict__ agg, const float* __restrict__ stats,
                                                const float* __restrict__ g, const float* __restrict__ b,
                                                const float* __restrict__ u, float* __restrict__ fout,
                                                float* __restrict__ logits, int n, float invN) {
    int d = threadIdx.x & 127;
    int which = threadIdx.x >> 7;
    int i = blockIdx.x * 2 + which;
    __shared__ float red[2][2];
    float c = 0.f;
    if (i < n) {
        float mean = stats[d] * invN;
        float ex2 = stats[d + DD] * invN;
        float var = ex2 - mean * mean;
        float f = (agg[(size_t)i * DD + d] - mean) * rsqrtf(var + EPS) * g[d] + b[d];
        f = fmaxf(f, 0.f);
        fout[(size_t)i * DD + d] = f;
        c = f * u[d];
    }
    #pragma unroll
    for (int off = 32; off; off >>= 1) c += __shfl_down(c, off);
    int lane = threadIdx.x & 63;
    int wv = (threadIdx.x >> 6) & 1;
    if (lane == 0) red[which][wv] = c;
    __syncthreads();
    if (i < n && (threadIdx.x & 127) == 0) logits[i] += red[which][0] + red[which][1];
}

// logits[i] = h[i] . u0
__global__ __launch_bounds__(256) void dot_init(const float* __restrict__ h, const float* __restrict__ u,
                                                float* __restrict__ logits, int n) {
    int d = threadIdx.x & 127;
    int which = threadIdx.x >> 7;
    int i = blockIdx.x * 2 + which;
    __shared__ float red[2][2];
    float c = 0.f;
    if (i < n) c = h[(size_t)i * DD + d] * u[d];
    #pragma unroll
    for (int off = 32; off; off >>= 1) c += __shfl_down(c, off);
    int lane = threadIdx.x & 63;
    int wv = (threadIdx.x >> 6) & 1;
    if (lane == 0) red[which][wv] = c;
    __syncthreads();
    if (i < n && (threadIdx.x & 127) == 0) logits[i] = red[which][0] + red[which][1];
}

__global__ __launch_bounds__(256) void finalize(const float* __restrict__ logits, float* __restrict__ out, int n) {
    int i = blockIdx.x * 256 + threadIdx.x;
    if (i < n) {
        float x = logits[i];
        out[i] = x;
        out[n + i] = 1.f / (1.f + expf(-x));
    }
}

// ---------------- host ----------------

static inline size_t align_up(size_t x, size_t a) { return (x + a - 1) & ~(a - 1); }

extern "C" void kernel_launch(void* const* d_in, const int* in_sizes, int n_in,
                              void* d_out, int out_size, void* d_ws, size_t ws_size,
                              hipStream_t stream) {
    const float* x       = (const float*)d_in[0];
    const int*   ei      = (const int*)d_in[1];      // int32 per harness contract
    const float* emb_w   = (const float*)d_in[2];
    const float* emb_b   = (const float*)d_in[3];
    const float* gcn_w   = (const float*)d_in[4];
    // d_in[5] = gcn_b: no-op (constant shift immediately normalized away by BatchNorm)
    const float* bn_g    = (const float*)d_in[6];
    const float* bn_b    = (const float*)d_in[7];
    const float* skip_w  = (const float*)d_in[8];
    const float* readout = (const float*)d_in[9];
    float* out = (float*)d_out;

    const int N = in_sizes[0] / DD;
    const int E = in_sizes[1] / 2;

    char* p = (char*)d_ws;
    size_t off = 0;
    auto alloc = [&](size_t bytes) { void* r = p + off; off = align_up(off + bytes, 256); return r; };
    int*   deg    = (int*)  alloc((size_t)N * 4);
    float* dis    = (float*)alloc((size_t)N * 4);
    int*   offs   = (int*)  alloc((size_t)(N + 1) * 4);
    int*   cursor = (int*)  alloc((size_t)N * 4);
    int*   ebuf   = (int*)  alloc((size_t)E * 4);
    int*   bsum   = (int*)  alloc((size_t)NB * 4);
    float* u      = (float*)alloc(4 * DD * 4);
    float* stats  = (float*)alloc(2 * DD * 4);
    float* logits = (float*)alloc((size_t)N * 4);
    float* buf0   = (float*)alloc((size_t)N * DD * 4);  // feats / agg (ping)
    float* buf1   = (float*)alloc((size_t)N * DD * 4);  // hl2 (pong)
    (void)ws_size;

    int gN = (N + 255) / 256;
    int gE = (E + 255) / 256;
    int gG = (N + 127) / 128;

    init_deg<<<gN, 256, 0, stream>>>(deg, N);
    count_deg<<<gE, 256, 0, stream>>>(ei, deg, E);
    dis_kernel<<<gN, 256, 0, stream>>>(deg, dis, N);
    scan1<<<NB, 256, 0, stream>>>(deg, bsum, N);
    scan2<<<1, NB, 0, stream>>>(bsum, offs, N);
    scan3<<<NB, 256, 0, stream>>>(deg, bsum, offs, cursor, N);
    fill_edges<<<gE, 256, 0, stream>>>(ei, cursor, ebuf, E);
    compute_u<<<4, DD, 0, stream>>>(skip_w, readout, u);

    // embedding: h = x @ emb_w + emb_b  -> buf0
    gemm128<<<gG, 256, 0, stream>>>(x, emb_w, emb_b, nullptr, buf0, N);
    dot_init<<<(N + 1) / 2, 256, 0, stream>>>(buf0, u, logits, N);

    for (int l = 0; l < 3; l++) {  // layer 3's output is dead (skip uses feats[0..3])
        // hl2 = (feats @ W) * dis[row]
        gemm128<<<gG, 256, 0, stream>>>(buf0, gcn_w + (size_t)l * DD * DD, nullptr, dis, buf1, N);
        aggregate<<<(N + 3) / 4, 256, 0, stream>>>(buf1, ebuf, offs, dis, buf0, N);
        zero_stats<<<1, 2 * DD, 0, stream>>>(stats);
        bn_stats<<<256, 256, 0, stream>>>(buf0, stats, N);
        bn_apply<<<(N + 1) / 2, 256, 0, stream>>>(buf0, stats, bn_g + l * DD, bn_b + l * DD,
                                                  u + (l + 1) * DD, buf0, logits, N, 1.0f / N);
    }
    finalize<<<gN, 256, 0, stream>>>(logits, out, N);
}

// Round 4
// 965.240 us; speedup vs baseline: 1.5119x; 1.1550x over previous
//
#include <hip/hip_runtime.h>
#include <hip/hip_bf16.h>
#include <math.h>

#define DD 128
#define EPS 1e-5f
#define NB 256

using bf16x8 = __attribute__((ext_vector_type(8))) __bf16;
using f32x4  = __attribute__((ext_vector_type(4))) float;
union U16B { uint4 u; bf16x8 b; };

// round-to-nearest-even f32 -> bf16 (bit trick; finite inputs)
__device__ inline ushort f2b(float f) {
    uint u = __float_as_uint(f);
    return (ushort)((u + 0x7fffu + ((u >> 16) & 1u)) >> 16);
}
__device__ inline float b2f(ushort h) { return __uint_as_float(((uint)h) << 16); }

// ---------------- preprocessing ----------------

__global__ __launch_bounds__(256) void init_deg(int* deg, int n) {
    int i = blockIdx.x * 256 + threadIdx.x;
    if (i < n) deg[i] = 1;  // self loop
}

__global__ __launch_bounds__(256) void count_deg(const int* __restrict__ ei, int* deg, int ne) {
    int e = blockIdx.x * 256 + threadIdx.x;
    if (e < ne) atomicAdd(&deg[ei[ne + e]], 1);  // col = target
}

__global__ __launch_bounds__(256) void dis_kernel(const int* __restrict__ deg, float* dis, int n) {
    int i = blockIdx.x * 256 + threadIdx.x;
    if (i < n) dis[i] = rsqrtf((float)deg[i]);
}

__global__ __launch_bounds__(256) void scan1(const int* __restrict__ deg, int* bsum, int n) {
    int b = blockIdx.x;
    int span = (n + NB - 1) / NB;
    int s0 = b * span, s1 = min(n, s0 + span);
    int tc = (span + 255) / 256;
    int t0 = s0 + threadIdx.x * tc, t1 = min(s1, t0 + tc);
    int local = 0;
    for (int i = t0; i < t1; i++) local += deg[i] - 1;
    __shared__ int sm[256];
    sm[threadIdx.x] = local;
    __syncthreads();
    for (int off = 128; off; off >>= 1) {
        if (threadIdx.x < off) sm[threadIdx.x] += sm[threadIdx.x + off];
        __syncthreads();
    }
    if (threadIdx.x == 0) bsum[b] = sm[0];
}

__global__ __launch_bounds__(NB) void scan2(int* bsum, int* offs, int n) {
    __shared__ int sm[NB];
    int t = threadIdx.x;
    sm[t] = bsum[t];
    __syncthreads();
    for (int off = 1; off < NB; off <<= 1) {
        int v = sm[t];
        int add = (t >= off) ? sm[t - off] : 0;
        __syncthreads();
        sm[t] = v + add;
        __syncthreads();
    }
    bsum[t] = (t == 0) ? 0 : sm[t - 1];
    if (t == NB - 1) offs[n] = sm[NB - 1];
}

__global__ __launch_bounds__(256) void scan3(const int* __restrict__ deg, const int* __restrict__ bsum,
                                             int* offs, int* cursor, int n) {
    int b = blockIdx.x;
    int span = (n + NB - 1) / NB;
    int s0 = b * span, s1 = min(n, s0 + span);
    int tc = (span + 255) / 256;
    int t0 = s0 + threadIdx.x * tc, t1 = min(s1, t0 + tc);
    int local = 0;
    for (int i = t0; i < t1; i++) local += deg[i] - 1;
    __shared__ int sm[256];
    int t = threadIdx.x;
    sm[t] = local;
    __syncthreads();
    for (int off = 1; off < 256; off <<= 1) {
        int v = sm[t];
        int add = (t >= off) ? sm[t - off] : 0;
        __syncthreads();
        sm[t] = v + add;
        __syncthreads();
    }
    int base = bsum[b] + ((t == 0) ? 0 : sm[t - 1]);
    for (int i = t0; i < t1; i++) {
        offs[i] = base;
        cursor[i] = base;
        base += deg[i] - 1;
    }
}

__global__ __launch_bounds__(256) void fill_edges(const int* __restrict__ ei, int* cursor, int* ebuf, int ne) {
    int e = blockIdx.x * 256 + threadIdx.x;
    if (e >= ne) return;
    int r = ei[e];        // source
    int c = ei[ne + e];   // target
    int pos = atomicAdd(&cursor[c], 1);
    ebuf[pos] = r;
}

__global__ void compute_u(const float* __restrict__ skip_w, const float* __restrict__ readout_w, float* u) {
    int i = blockIdx.x;
    int d = threadIdx.x;
    float s = 0.f;
    const float* sw = skip_w + i * DD * DD + d * DD;
    const float* rw = readout_w + i * DD;
    for (int j = 0; j < DD; j++) s += sw[j] * rw[j];
    u[i * DD + d] = s;
}

// weights -> bf16, transposed to WT[n][k] so MFMA B-frags are contiguous
__global__ __launch_bounds__(256) void prep_w(const float* __restrict__ emb_w, const float* __restrict__ gcn_w,
                                              ushort* __restrict__ WTall) {
    int b = blockIdx.x;  // 0 = emb, 1..3 = gcn layer b-1
    const float* W = (b == 0) ? emb_w : gcn_w + (size_t)(b - 1) * DD * DD;
    ushort* WT = WTall + (size_t)b * DD * DD;
    for (int i = threadIdx.x; i < DD * DD; i += 256) {
        int k = i >> 7, nn = i & 127;
        WT[nn * DD + k] = f2b(W[i]);
    }
}

__global__ __launch_bounds__(256) void cvt_f2b(const float* __restrict__ in, ushort* __restrict__ outb, int n4) {
    int i = blockIdx.x * 256 + threadIdx.x;
    if (i < n4) {
        float4 v = *(const float4*)(in + (size_t)i * 4);
        ushort4 o;
        o.x = f2b(v.x); o.y = f2b(v.y); o.z = f2b(v.z); o.w = f2b(v.w);
        *(ushort4*)(outb + (size_t)i * 4) = o;
    }
}

// ---------------- MFMA GEMM: Y = ((X @ W) + bias) * scale[row], all bf16 I/O ----------------
// 256 thr = 4 waves; block computes 128 rows; wave w: rows w*32..w*32+31 (2 m-tiles), 8 n-tiles.
// A frag: lane holds X[row0+ (l&15)][ks*32 + (l>>4)*8 ..+7]; B frag from WT[n][k] same pattern.
// C/D: col = lane&15, row = (lane>>4)*4 + r   [verified m89/m91 mapping]
__global__ __launch_bounds__(256) void gemm_mfma(const ushort* __restrict__ X, const ushort* __restrict__ WT,
                                                 const float* __restrict__ bias, const float* __restrict__ scale,
                                                 ushort* __restrict__ Y, int nrows) {
    int wv = threadIdx.x >> 6;
    int lane = threadIdx.x & 63;
    int l15 = lane & 15;
    int kg = lane >> 4;
    int row0 = blockIdx.x * 128 + wv * 32;

    f32x4 acc[2][8];
    #pragma unroll
    for (int mt = 0; mt < 2; mt++)
        #pragma unroll
        for (int nt = 0; nt < 8; nt++) acc[mt][nt] = (f32x4){0.f, 0.f, 0.f, 0.f};

    int rA0 = min(row0 + l15, nrows - 1);
    int rA1 = min(row0 + 16 + l15, nrows - 1);
    const uint4* xa0 = (const uint4*)(X + (size_t)rA0 * DD);
    const uint4* xa1 = (const uint4*)(X + (size_t)rA1 * DD);

    #pragma unroll
    for (int ks = 0; ks < 4; ks++) {
        U16B a0, a1;
        a0.u = xa0[ks * 4 + kg];
        a1.u = xa1[ks * 4 + kg];
        #pragma unroll
        for (int nt = 0; nt < 8; nt++) {
            U16B b;
            b.u = ((const uint4*)(WT + (size_t)(nt * 16 + l15) * DD))[ks * 4 + kg];
            acc[0][nt] = __builtin_amdgcn_mfma_f32_16x16x32_bf16(a0.b, b.b, acc[0][nt], 0, 0, 0);
            acc[1][nt] = __builtin_amdgcn_mfma_f32_16x16x32_bf16(a1.b, b.b, acc[1][nt], 0, 0, 0);
        }
    }

    #pragma unroll
    for (int mt = 0; mt < 2; mt++) {
        #pragma unroll
        for (int r = 0; r < 4; r++) {
            int row = row0 + mt * 16 + kg * 4 + r;
            if (row < nrows) {
                float s = scale ? scale[row] : 1.f;
                #pragma unroll
                for (int nt = 0; nt < 8; nt++) {
                    int col = nt * 16 + l15;
                    float v = acc[mt][nt][r];
                    if (bias) v += bias[col];
                    Y[(size_t)row * DD + col] = f2b(v * s);
                }
            }
        }
    }
}

// ---------------- aggregation: one wave per node, bf16 gather, fp32 accumulate ----------------
// hl2 carries dis[src]: agg[v] = dis[v] * ( hl2[v] + sum_{e: col=v} hl2[src] )
__global__ __launch_bounds__(256) void aggregate(const ushort* __restrict__ hl2, const int* __restrict__ ebuf,
                                                 const int* __restrict__ offs, const float* __restrict__ dis,
                                                 float* __restrict__ agg, int n) {
    int w = threadIdx.x >> 6;
    int lane = threadIdx.x & 63;
    int v = blockIdx.x * 4 + w;
    if (v >= n) return;
    uint self = ((const uint*)(hl2 + (size_t)v * DD))[lane];
    float ax = __uint_as_float(self << 16);
    float ay = __uint_as_float(self & 0xffff0000u);
    int e0 = offs[v], e1 = offs[v + 1];
    int src_next = (e0 < e1) ? ebuf[e0] : 0;
    for (int e = e0; e < e1; e++) {
        int src = src_next;
        if (e + 1 < e1) src_next = ebuf[e + 1];
        uint m = ((const uint*)(hl2 + (size_t)src * DD))[lane];
        ax += __uint_as_float(m << 16);
        ay += __uint_as_float(m & 0xffff0000u);
    }
    float dv = dis[v];
    float2 o; o.x = ax * dv; o.y = ay * dv;
    ((float2*)(agg + (size_t)v * DD))[lane] = o;
}

// ---------------- batchnorm ----------------

__global__ void zero_stats(float* stats) { stats[threadIdx.x] = 0.f; }

__global__ __launch_bounds__(256) void bn_stats(const float* __restrict__ agg, float* stats, int n) {
    int d = threadIdx.x & 127;
    int rg = threadIdx.x >> 7;
    float s = 0.f, s2 = 0.f;
    for (int i = blockIdx.x * 2 + rg; i < n; i += gridDim.x * 2) {
        float v = agg[(size_t)i * DD + d];
        s += v; s2 += v * v;
    }
    __shared__ float ls[2][DD], ls2[2][DD];
    ls[rg][d] = s; ls2[rg][d] = s2;
    __syncthreads();
    if (rg == 0) {
        atomicAdd(&stats[d], ls[0][d] + ls[1][d]);
        atomicAdd(&stats[d + DD], ls2[0][d] + ls2[1][d]);
    }
}

// BN + relu + write bf16 feats + logits += f . u  (f kept fp32 for the dot)
__global__ __launch_bounds__(256) void bn_apply(const float* __restrict__ agg, const float* __restrict__ stats,
                                                const float* __restrict__ g, const float* __restrict__ b,
                                                const float* __restrict__ u, ushort* __restrict__ fout,
                                                float* __restrict__ logits, int n, float invN) {
    int d = threadIdx.x & 127;
    int which = threadIdx.x >> 7;
    int i = blockIdx.x * 2 + which;
    __shared__ float red[2][2];
    float c = 0.f;
    if (i < n) {
        float mean = stats[d] * invN;
        float ex2 = stats[d + DD] * invN;
        float var = ex2 - mean * mean;
        float f = (agg[(size_t)i * DD + d] - mean) * rsqrtf(var + EPS) * g[d] + b[d];
        f = fmaxf(f, 0.f);
        fout[(size_t)i * DD + d] = f2b(f);
        c = f * u[d];
    }
    #pragma unroll
    for (int off = 32; off; off >>= 1) c += __shfl_down(c, off);
    int lane = threadIdx.x & 63;
    int wv = (threadIdx.x >> 6) & 1;
    if (lane == 0) red[which][wv] = c;
    __syncthreads();
    if (i < n && (threadIdx.x & 127) == 0) logits[i] += red[which][0] + red[which][1];
}

// logits[i] = h[i] . u0   (h in bf16)
__global__ __launch_bounds__(256) void dot_init(const ushort* __restrict__ h, const float* __restrict__ u,
                                                float* __restrict__ logits, int n) {
    int d = threadIdx.x & 127;
    int which = threadIdx.x >> 7;
    int i = blockIdx.x * 2 + which;
    __shared__ float red[2][2];
    float c = 0.f;
    if (i < n) c = b2f(h[(size_t)i * DD + d]) * u[d];
    #pragma unroll
    for (int off = 32; off; off >>= 1) c += __shfl_down(c, off);
    int lane = threadIdx.x & 63;
    int wv = (threadIdx.x >> 6) & 1;
    if (lane == 0) red[which][wv] = c;
    __syncthreads();
    if (i < n && (threadIdx.x & 127) == 0) logits[i] = red[which][0] + red[which][1];
}

__global__ __launch_bounds__(256) void finalize(const float* __restrict__ logits, float* __restrict__ out, int n) {
    int i = blockIdx.x * 256 + threadIdx.x;
    if (i < n) {
        float x = logits[i];
        out[i] = x;
        out[n + i] = 1.f / (1.f + expf(-x));
    }
}

// ---------------- host ----------------

static inline size_t align_up(size_t x, size_t a) { return (x + a - 1) & ~(a - 1); }

extern "C" void kernel_launch(void* const* d_in, const int* in_sizes, int n_in,
                              void* d_out, int out_size, void* d_ws, size_t ws_size,
                              hipStream_t stream) {
    const float* x       = (const float*)d_in[0];
    const int*   ei      = (const int*)d_in[1];      // int32 per harness contract
    const float* emb_w   = (const float*)d_in[2];
    const float* emb_b   = (const float*)d_in[3];
    const float* gcn_w   = (const float*)d_in[4];
    // d_in[5] = gcn_b: no-op (constant shift immediately normalized away by BatchNorm)
    const float* bn_g    = (const float*)d_in[6];
    const float* bn_b    = (const float*)d_in[7];
    const float* skip_w  = (const float*)d_in[8];
    const float* readout = (const float*)d_in[9];
    float* out = (float*)d_out;

    const int N = in_sizes[0] / DD;
    const int E = in_sizes[1] / 2;

    char* p = (char*)d_ws;
    size_t off = 0;
    auto alloc = [&](size_t bytes) { void* r = p + off; off = align_up(off + bytes, 256); return r; };
    int*    deg    = (int*)   alloc((size_t)N * 4);
    float*  dis    = (float*) alloc((size_t)N * 4);
    int*    offs   = (int*)   alloc((size_t)(N + 1) * 4);
    int*    cursor = (int*)   alloc((size_t)N * 4);
    int*    ebuf   = (int*)   alloc((size_t)E * 4);
    int*    bsum   = (int*)   alloc((size_t)NB * 4);
    float*  u      = (float*) alloc(4 * DD * 4);
    float*  stats  = (float*) alloc(2 * DD * 4);
    ushort* WTall  = (ushort*)alloc(4 * (size_t)DD * DD * 2);
    float*  logits = (float*) alloc((size_t)N * 4);
    ushort* featsB = (ushort*)alloc((size_t)N * DD * 2);   // bf16 feats
    ushort* hl2B   = (ushort*)alloc((size_t)N * DD * 2);   // bf16 hl2
    float*  aggF   = (float*) alloc((size_t)N * DD * 4);   // fp32 aggregation
    ushort* xB     = (ushort*)aggF;                        // alias: xB dead before aggF first written
    (void)ws_size;

    int gN = (N + 255) / 256;
    int gE = (E + 255) / 256;
    int gG = (N + 127) / 128;

    init_deg<<<gN, 256, 0, stream>>>(deg, N);
    count_deg<<<gE, 256, 0, stream>>>(ei, deg, E);
    dis_kernel<<<gN, 256, 0, stream>>>(deg, dis, N);
    scan1<<<NB, 256, 0, stream>>>(deg, bsum, N);
    scan2<<<1, NB, 0, stream>>>(bsum, offs, N);
    scan3<<<NB, 256, 0, stream>>>(deg, bsum, offs, cursor, N);
    fill_edges<<<gE, 256, 0, stream>>>(ei, cursor, ebuf, E);
    compute_u<<<4, DD, 0, stream>>>(skip_w, readout, u);
    prep_w<<<4, 256, 0, stream>>>(emb_w, gcn_w, WTall);
    cvt_f2b<<<(N * DD / 4 + 255) / 256, 256, 0, stream>>>(x, xB, N * DD / 4);

    // embedding: h = x @ emb_w + emb_b  -> featsB (bf16)
    gemm_mfma<<<gG, 256, 0, stream>>>(xB, WTall, emb_b, nullptr, featsB, N);
    dot_init<<<(N + 1) / 2, 256, 0, stream>>>(featsB, u, logits, N);

    for (int l = 0; l < 3; l++) {  // layer 3's output is dead (skip uses feats[0..3])
        // hl2 = (feats @ W) * dis[row]  (bf16 out)
        gemm_mfma<<<gG, 256, 0, stream>>>(featsB, WTall + (size_t)(l + 1) * DD * DD, nullptr, dis, hl2B, N);
        aggregate<<<(N + 3) / 4, 256, 0, stream>>>(hl2B, ebuf, offs, dis, aggF, N);
        zero_stats<<<1, 2 * DD, 0, stream>>>(stats);
        bn_stats<<<256, 256, 0, stream>>>(aggF, stats, N);
        bn_apply<<<(N + 1) / 2, 256, 0, stream>>>(aggF, stats, bn_g + l * DD, bn_b + l * DD,
                                                  u + (l + 1) * DD, featsB, logits, N, 1.0f / N);
    }
    finalize<<<gN, 256, 0, stream>>>(logits, out, N);
}

// Round 5
// 961.641 us; speedup vs baseline: 1.5175x; 1.0037x over previous
//
#include <hip/hip_runtime.h>
#include <hip/hip_bf16.h>
#include <math.h>

#define DD 128
#define EPS 1e-5f
#define NB 256

using bf16x8 = __attribute__((ext_vector_type(8))) __bf16;
using f32x4  = __attribute__((ext_vector_type(4))) float;
union U16B { uint4 u; bf16x8 b; };

__device__ inline ushort f2b(float f) {
    uint u = __float_as_uint(f);
    return (ushort)((u + 0x7fffu + ((u >> 16) & 1u)) >> 16);
}
__device__ inline float b2f(ushort h) { return __uint_as_float(((uint)h) << 16); }

// ---------------- preprocessing ----------------

__global__ __launch_bounds__(256) void init_deg(int* deg, int n) {
    int i = blockIdx.x * 256 + threadIdx.x;
    if (i < n) deg[i] = 1;  // self loop
}

__global__ __launch_bounds__(256) void count_deg(const int* __restrict__ ei, int* deg, int ne) {
    int e = blockIdx.x * 256 + threadIdx.x;
    if (e < ne) atomicAdd(&deg[ei[ne + e]], 1);  // col = target
}

__global__ __launch_bounds__(256) void dis_kernel(const int* __restrict__ deg, float* dis, int n) {
    int i = blockIdx.x * 256 + threadIdx.x;
    if (i < n) dis[i] = rsqrtf((float)deg[i]);
}

__global__ __launch_bounds__(256) void scan1(const int* __restrict__ deg, int* bsum, int n) {
    int b = blockIdx.x;
    int span = (n + NB - 1) / NB;
    int s0 = b * span, s1 = min(n, s0 + span);
    int tc = (span + 255) / 256;
    int t0 = s0 + threadIdx.x * tc, t1 = min(s1, t0 + tc);
    int local = 0;
    for (int i = t0; i < t1; i++) local += deg[i] - 1;
    __shared__ int sm[256];
    sm[threadIdx.x] = local;
    __syncthreads();
    for (int off = 128; off; off >>= 1) {
        if (threadIdx.x < off) sm[threadIdx.x] += sm[threadIdx.x + off];
        __syncthreads();
    }
    if (threadIdx.x == 0) bsum[b] = sm[0];
}

__global__ __launch_bounds__(NB) void scan2(int* bsum, int* offs, int n) {
    __shared__ int sm[NB];
    int t = threadIdx.x;
    sm[t] = bsum[t];
    __syncthreads();
    for (int off = 1; off < NB; off <<= 1) {
        int v = sm[t];
        int add = (t >= off) ? sm[t - off] : 0;
        __syncthreads();
        sm[t] = v + add;
        __syncthreads();
    }
    bsum[t] = (t == 0) ? 0 : sm[t - 1];
    if (t == NB - 1) offs[n] = sm[NB - 1];
}

__global__ __launch_bounds__(256) void scan3(const int* __restrict__ deg, const int* __restrict__ bsum,
                                             int* offs, int n) {
    int b = blockIdx.x;
    int span = (n + NB - 1) / NB;
    int s0 = b * span, s1 = min(n, s0 + span);
    int tc = (span + 255) / 256;
    int t0 = s0 + threadIdx.x * tc, t1 = min(s1, t0 + tc);
    int local = 0;
    for (int i = t0; i < t1; i++) local += deg[i] - 1;
    __shared__ int sm[256];
    int t = threadIdx.x;
    sm[t] = local;
    __syncthreads();
    for (int off = 1; off < 256; off <<= 1) {
        int v = sm[t];
        int add = (t >= off) ? sm[t - off] : 0;
        __syncthreads();
        sm[t] = v + add;
        __syncthreads();
    }
    int base = bsum[b] + ((t == 0) ? 0 : sm[t - 1]);
    for (int i = t0; i < t1; i++) {
        offs[i] = base;
        base += deg[i] - 1;
    }
}

// ---- bucketed CSR fill: bucket = 64 consecutive nodes; bucket CSR window = offs[b*64]..offs[(b+1)*64] ----

__global__ __launch_bounds__(256) void init_bukcur(const int* __restrict__ offs, int* bukcur, int nbuk) {
    int b = blockIdx.x * 256 + threadIdx.x;
    if (b < nbuk) bukcur[b] = offs[b * 64];
}

// scatter (src, c&63) packed into the target bucket's CSR window (random only within ~4KB)
__global__ __launch_bounds__(256) void scatter_pairs(const int* __restrict__ ei, int* bukcur,
                                                     uint* __restrict__ pairs, int ne) {
    int e = blockIdx.x * 256 + threadIdx.x;
    if (e >= ne) return;
    int r = ei[e];        // source
    int c = ei[ne + e];   // target
    int pos = atomicAdd(&bukcur[c >> 6], 1);
    pairs[pos] = ((uint)r << 6) | (uint)(c & 63);
}

// per-bucket: place each edge at its node's exact CSR slot (LDS cursors, window-local writes)
__global__ __launch_bounds__(256) void csr_finalize(const uint* __restrict__ pairs, const int* __restrict__ offs,
                                                    int* __restrict__ ebuf, int n) {
    __shared__ int cur[64];
    int b = blockIdx.x;
    int t = threadIdx.x;
    int node0 = b * 64;
    if (t < 64) cur[t] = offs[min(node0 + t, n)];
    __syncthreads();
    int base = offs[node0];
    int end  = offs[min(node0 + 64, n)];
    for (int e = base + t; e < end; e += 256) {
        uint p = pairs[e];
        int cl = (int)(p & 63u);
        int src = (int)(p >> 6);
        int pos = atomicAdd(&cur[cl], 1);
        ebuf[pos] = src;
    }
}

__global__ void compute_u(const float* __restrict__ skip_w, const float* __restrict__ readout_w, float* u) {
    int i = blockIdx.x;
    int d = threadIdx.x;
    float s = 0.f;
    const float* sw = skip_w + i * DD * DD + d * DD;
    const float* rw = readout_w + i * DD;
    for (int j = 0; j < DD; j++) s += sw[j] * rw[j];
    u[i * DD + d] = s;
}

__global__ __launch_bounds__(256) void prep_w(const float* __restrict__ emb_w, const float* __restrict__ gcn_w,
                                              ushort* __restrict__ WTall) {
    int b = blockIdx.x;  // 0 = emb, 1..3 = gcn layer b-1
    const float* W = (b == 0) ? emb_w : gcn_w + (size_t)(b - 1) * DD * DD;
    ushort* WT = WTall + (size_t)b * DD * DD;
    for (int i = threadIdx.x; i < DD * DD; i += 256) {
        int k = i >> 7, nn = i & 127;
        WT[nn * DD + k] = f2b(W[i]);
    }
}

__global__ __launch_bounds__(256) void cvt_f2b(const float* __restrict__ in, ushort* __restrict__ outb, int n4) {
    int i = blockIdx.x * 256 + threadIdx.x;
    if (i < n4) {
        float4 v = *(const float4*)(in + (size_t)i * 4);
        ushort4 o;
        o.x = f2b(v.x); o.y = f2b(v.y); o.z = f2b(v.z); o.w = f2b(v.w);
        *(ushort4*)(outb + (size_t)i * 4) = o;
    }
}

// ---------------- MFMA GEMM: Y = ((X @ W) + bias) * scale[row], bf16 I/O ----------------
__global__ __launch_bounds__(256) void gemm_mfma(const ushort* __restrict__ X, const ushort* __restrict__ WT,
                                                 const float* __restrict__ bias, const float* __restrict__ scale,
                                                 ushort* __restrict__ Y, int nrows) {
    int wv = threadIdx.x >> 6;
    int lane = threadIdx.x & 63;
    int l15 = lane & 15;
    int kg = lane >> 4;
    int row0 = blockIdx.x * 128 + wv * 32;

    f32x4 acc[2][8];
    #pragma unroll
    for (int mt = 0; mt < 2; mt++)
        #pragma unroll
        for (int nt = 0; nt < 8; nt++) acc[mt][nt] = (f32x4){0.f, 0.f, 0.f, 0.f};

    int rA0 = min(row0 + l15, nrows - 1);
    int rA1 = min(row0 + 16 + l15, nrows - 1);
    const uint4* xa0 = (const uint4*)(X + (size_t)rA0 * DD);
    const uint4* xa1 = (const uint4*)(X + (size_t)rA1 * DD);

    #pragma unroll
    for (int ks = 0; ks < 4; ks++) {
        U16B a0, a1;
        a0.u = xa0[ks * 4 + kg];
        a1.u = xa1[ks * 4 + kg];
        #pragma unroll
        for (int nt = 0; nt < 8; nt++) {
            U16B b;
            b.u = ((const uint4*)(WT + (size_t)(nt * 16 + l15) * DD))[ks * 4 + kg];
            acc[0][nt] = __builtin_amdgcn_mfma_f32_16x16x32_bf16(a0.b, b.b, acc[0][nt], 0, 0, 0);
            acc[1][nt] = __builtin_amdgcn_mfma_f32_16x16x32_bf16(a1.b, b.b, acc[1][nt], 0, 0, 0);
        }
    }

    #pragma unroll
    for (int mt = 0; mt < 2; mt++) {
        #pragma unroll
        for (int r = 0; r < 4; r++) {
            int row = row0 + mt * 16 + kg * 4 + r;
            if (row < nrows) {
                float s = scale ? scale[row] : 1.f;
                #pragma unroll
                for (int nt = 0; nt < 8; nt++) {
                    int col = nt * 16 + l15;
                    float v = acc[mt][nt][r];
                    if (bias) v += bias[col];
                    Y[(size_t)row * DD + col] = f2b(v * s);
                }
            }
        }
    }
}

// ---------------- aggregation: one wave per node, 2-edge unroll for MLP ----------------
__global__ __launch_bounds__(256) void aggregate(const ushort* __restrict__ hl2, const int* __restrict__ ebuf,
                                                 const int* __restrict__ offs, const float* __restrict__ dis,
                                                 float* __restrict__ agg, int n) {
    int w = threadIdx.x >> 6;
    int lane = threadIdx.x & 63;
    int v = blockIdx.x * 4 + w;
    if (v >= n) return;
    uint self = ((const uint*)(hl2 + (size_t)v * DD))[lane];
    float ax = __uint_as_float(self << 16);
    float ay = __uint_as_float(self & 0xffff0000u);
    float bx = 0.f, by = 0.f;
    int e0 = offs[v], e1 = offs[v + 1];
    int e = e0;
    for (; e + 1 < e1; e += 2) {
        int s0 = ebuf[e], s1 = ebuf[e + 1];
        uint m0 = ((const uint*)(hl2 + (size_t)s0 * DD))[lane];
        uint m1 = ((const uint*)(hl2 + (size_t)s1 * DD))[lane];
        ax += __uint_as_float(m0 << 16);
        ay += __uint_as_float(m0 & 0xffff0000u);
        bx += __uint_as_float(m1 << 16);
        by += __uint_as_float(m1 & 0xffff0000u);
    }
    if (e < e1) {
        uint m = ((const uint*)(hl2 + (size_t)ebuf[e] * DD))[lane];
        ax += __uint_as_float(m << 16);
        ay += __uint_as_float(m & 0xffff0000u);
    }
    float dv = dis[v];
    float2 o; o.x = (ax + bx) * dv; o.y = (ay + by) * dv;
    ((float2*)(agg + (size_t)v * DD))[lane] = o;
}

// ---------------- batchnorm ----------------

__global__ void zero_stats(float* stats) { stats[threadIdx.x] = 0.f; }

__global__ __launch_bounds__(1024) void bn_stats(const float* __restrict__ agg, float* stats, int n) {
    int d = threadIdx.x & 127;
    int rg = threadIdx.x >> 7;   // 0..7
    float s = 0.f, s2 = 0.f;
    for (int i = blockIdx.x * 8 + rg; i < n; i += gridDim.x * 8) {
        float v = agg[(size_t)i * DD + d];
        s += v; s2 += v * v;
    }
    __shared__ float ls[8][DD], ls2[8][DD];
    ls[rg][d] = s; ls2[rg][d] = s2;
    __syncthreads();
    if (rg == 0) {
        float a = 0.f, a2 = 0.f;
        #pragma unroll
        for (int r = 0; r < 8; r++) { a += ls[r][d]; a2 += ls2[r][d]; }
        atomicAdd(&stats[d], a);
        atomicAdd(&stats[d + DD], a2);
    }
}

__global__ __launch_bounds__(256) void bn_apply(const float* __restrict__ agg, const float* __restrict__ stats,
                                                const float* __restrict__ g, const float* __restrict__ b,
                                                const float* __restrict__ u, ushort* __restrict__ fout,
                                                float* __restrict__ logits, int n, float invN) {
    int d = threadIdx.x & 127;
    int which = threadIdx.x >> 7;
    int i = blockIdx.x * 2 + which;
    __shared__ float red[2][2];
    float c = 0.f;
    if (i < n) {
        float mean = stats[d] * invN;
        float ex2 = stats[d + DD] * invN;
        float var = ex2 - mean * mean;
        float f = (agg[(size_t)i * DD + d] - mean) * rsqrtf(var + EPS) * g[d] + b[d];
        f = fmaxf(f, 0.f);
        fout[(size_t)i * DD + d] = f2b(f);
        c = f * u[d];
    }
    #pragma unroll
    for (int off = 32; off; off >>= 1) c += __shfl_down(c, off);
    int lane = threadIdx.x & 63;
    int wv = (threadIdx.x >> 6) & 1;
    if (lane == 0) red[which][wv] = c;
    __syncthreads();
    if (i < n && (threadIdx.x & 127) == 0) logits[i] += red[which][0] + red[which][1];
}

__global__ __launch_bounds__(256) void dot_init(const ushort* __restrict__ h, const float* __restrict__ u,
                                                float* __restrict__ logits, int n) {
    int d = threadIdx.x & 127;
    int which = threadIdx.x >> 7;
    int i = blockIdx.x * 2 + which;
    __shared__ float red[2][2];
    float c = 0.f;
    if (i < n) c = b2f(h[(size_t)i * DD + d]) * u[d];
    #pragma unroll
    for (int off = 32; off; off >>= 1) c += __shfl_down(c, off);
    int lane = threadIdx.x & 63;
    int wv = (threadIdx.x >> 6) & 1;
    if (lane == 0) red[which][wv] = c;
    __syncthreads();
    if (i < n && (threadIdx.x & 127) == 0) logits[i] = red[which][0] + red[which][1];
}

__global__ __launch_bounds__(256) void finalize(const float* __restrict__ logits, float* __restrict__ out, int n) {
    int i = blockIdx.x * 256 + threadIdx.x;
    if (i < n) {
        float x = logits[i];
        out[i] = x;
        out[n + i] = 1.f / (1.f + expf(-x));
    }
}

// ---------------- host ----------------

static inline size_t align_up(size_t x, size_t a) { return (x + a - 1) & ~(a - 1); }

extern "C" void kernel_launch(void* const* d_in, const int* in_sizes, int n_in,
                              void* d_out, int out_size, void* d_ws, size_t ws_size,
                              hipStream_t stream) {
    const float* x       = (const float*)d_in[0];
    const int*   ei      = (const int*)d_in[1];
    const float* emb_w   = (const float*)d_in[2];
    const float* emb_b   = (const float*)d_in[3];
    const float* gcn_w   = (const float*)d_in[4];
    // d_in[5] = gcn_b: no-op (constant shift immediately normalized away by BatchNorm)
    const float* bn_g    = (const float*)d_in[6];
    const float* bn_b    = (const float*)d_in[7];
    const float* skip_w  = (const float*)d_in[8];
    const float* readout = (const float*)d_in[9];
    float* out = (float*)d_out;

    const int N = in_sizes[0] / DD;
    const int E = in_sizes[1] / 2;
    const int NBUK = (N + 63) / 64;

    char* p = (char*)d_ws;
    size_t off = 0;
    auto alloc = [&](size_t bytes) { void* r = p + off; off = align_up(off + bytes, 256); return r; };
    int*    deg    = (int*)   alloc((size_t)N * 4);
    float*  dis    = (float*) alloc((size_t)N * 4);
    int*    offs   = (int*)   alloc((size_t)(N + 1) * 4);
    int*    bukcur = (int*)   alloc((size_t)NBUK * 4);
    int*    ebuf   = (int*)   alloc((size_t)E * 4);
    uint*   pairs  = (uint*)  alloc((size_t)E * 4);
    int*    bsum   = (int*)   alloc((size_t)NB * 4);
    float*  u      = (float*) alloc(4 * DD * 4);
    float*  stats  = (float*) alloc(2 * DD * 4);
    ushort* WTall  = (ushort*)alloc(4 * (size_t)DD * DD * 2);
    float*  logits = (float*) alloc((size_t)N * 4);
    ushort* featsB = (ushort*)alloc((size_t)N * DD * 2);
    ushort* hl2B   = (ushort*)alloc((size_t)N * DD * 2);
    float*  aggF   = (float*) alloc((size_t)N * DD * 4);
    ushort* xB     = (ushort*)aggF;   // alias: xB dead before aggF first written
    (void)ws_size;

    int gN = (N + 255) / 256;
    int gE = (E + 255) / 256;
    int gG = (N + 127) / 128;

    init_deg<<<gN, 256, 0, stream>>>(deg, N);
    count_deg<<<gE, 256, 0, stream>>>(ei, deg, E);
    dis_kernel<<<gN, 256, 0, stream>>>(deg, dis, N);
    scan1<<<NB, 256, 0, stream>>>(deg, bsum, N);
    scan2<<<1, NB, 0, stream>>>(bsum, offs, N);
    scan3<<<NB, 256, 0, stream>>>(deg, bsum, offs, N);
    init_bukcur<<<(NBUK + 255) / 256, 256, 0, stream>>>(offs, bukcur, NBUK);
    scatter_pairs<<<gE, 256, 0, stream>>>(ei, bukcur, pairs, E);
    csr_finalize<<<NBUK, 256, 0, stream>>>(pairs, offs, ebuf, N);
    compute_u<<<4, DD, 0, stream>>>(skip_w, readout, u);
    prep_w<<<4, 256, 0, stream>>>(emb_w, gcn_w, WTall);
    cvt_f2b<<<(N * DD / 4 + 255) / 256, 256, 0, stream>>>(x, xB, N * DD / 4);

    gemm_mfma<<<gG, 256, 0, stream>>>(xB, WTall, emb_b, nullptr, featsB, N);
    dot_init<<<(N + 1) / 2, 256, 0, stream>>>(featsB, u, logits, N);

    for (int l = 0; l < 3; l++) {  // layer 3's output is dead (skip uses feats[0..3])
        gemm_mfma<<<gG, 256, 0, stream>>>(featsB, WTall + (size_t)(l + 1) * DD * DD, nullptr, dis, hl2B, N);
        aggregate<<<(N + 3) / 4, 256, 0, stream>>>(hl2B, ebuf, offs, dis, aggF, N);
        zero_stats<<<1, 2 * DD, 0, stream>>>(stats);
        bn_stats<<<256, 1024, 0, stream>>>(aggF, stats, N);
        bn_apply<<<(N + 1) / 2, 256, 0, stream>>>(aggF, stats, bn_g + l * DD, bn_b + l * DD,
                                                  u + (l + 1) * DD, featsB, logits, N, 1.0f / N);
    }
    finalize<<<gN, 256, 0, stream>>>(logits, out, N);
}

// Round 6
// 689.026 us; speedup vs baseline: 2.1179x; 1.3957x over previous
//
#include <hip/hip_runtime.h>
#include <hip/hip_bf16.h>
#include <math.h>

#define DD 128
#define EPS 1e-5f
#define GCH 512      // histogram/scatter chunks (must equal scatter grid)
#define MAXBUK 1600  // >= ceil(N/64); N=100000 -> 1563

using bf16x8 = __attribute__((ext_vector_type(8))) __bf16;
using f32x4  = __attribute__((ext_vector_type(4))) float;
union U16B { uint4 u; bf16x8 b; };

__device__ inline ushort f2b(float f) {
    uint u = __float_as_uint(f);
    return (ushort)((u + 0x7fffu + ((u >> 16) & 1u)) >> 16);
}
__device__ inline float b2f(ushort h) { return __uint_as_float(((uint)h) << 16); }

// ---------------- CSR build: contention-free counting sort ----------------
// bucket k = nodes [k*64, k*64+64); edge's bucket from its target (col).

// per-chunk LDS histogram of target buckets -> gh[g][k]
__global__ __launch_bounds__(256) void count_hist(const int* __restrict__ ei, int* __restrict__ gh,
                                                  int ne, int nbuk) {
    __shared__ int hist[MAXBUK];
    for (int i = threadIdx.x; i < nbuk; i += 256) hist[i] = 0;
    __syncthreads();
    int chunk = (ne + GCH - 1) / GCH;
    int e0 = blockIdx.x * chunk, e1 = min(ne, e0 + chunk);
    for (int e = e0 + threadIdx.x; e < e1; e += 256)
        atomicAdd(&hist[ei[ne + e] >> 6], 1);
    __syncthreads();
    for (int i = threadIdx.x; i < nbuk; i += 256)
        gh[(size_t)blockIdx.x * nbuk + i] = hist[i];
}

// per-bucket exclusive scan over the GCH chunks; gh[g][k] -> prefix, total[k] = sum
__global__ __launch_bounds__(256) void colscan(int* __restrict__ gh, int* __restrict__ total, int nbuk) {
    int k = blockIdx.x * 4 + (threadIdx.x >> 6);
    int lane = threadIdx.x & 63;
    if (k >= nbuk) return;
    const int PER = GCH / 64;  // 8
    int v[PER]; int s = 0;
    #pragma unroll
    for (int j = 0; j < PER; j++) { v[j] = gh[(size_t)(PER * lane + j) * nbuk + k]; s += v[j]; }
    int ps = s;
    #pragma unroll
    for (int off = 1; off < 64; off <<= 1) { int t = __shfl_up(ps, off); if (lane >= off) ps += t; }
    int run = ps - s;  // exclusive prefix of this lane's first chunk
    #pragma unroll
    for (int j = 0; j < PER; j++) { gh[(size_t)(PER * lane + j) * nbuk + k] = run; run += v[j]; }
    if (lane == 63) total[k] = run;
}

// exclusive scan of bucket totals -> bukbase[0..nbuk]; also offs[n] = ne
__global__ __launch_bounds__(1024) void bukscan(const int* __restrict__ total, int* __restrict__ bukbase,
                                                int* __restrict__ offs, int nbuk, int n, int ne) {
    __shared__ int sm[2048];
    int t = threadIdx.x;
    sm[t] = (t < nbuk) ? total[t] : 0;
    sm[t + 1024] = (t + 1024 < nbuk) ? total[t + 1024] : 0;
    __syncthreads();
    for (int off = 1; off < 2048; off <<= 1) {
        int a = sm[t],        b = (t >= off) ? sm[t - off] : 0;
        int a2 = sm[t + 1024], b2 = (t + 1024 >= off) ? sm[t + 1024 - off] : 0;
        __syncthreads();
        sm[t] = a + b; sm[t + 1024] = a2 + b2;
        __syncthreads();
    }
    if (t < nbuk) bukbase[t] = (t == 0) ? 0 : sm[t - 1];
    int u2 = t + 1024;
    if (u2 < nbuk) bukbase[u2] = sm[u2 - 1];
    if (t == 0) { bukbase[nbuk] = sm[nbuk - 1]; offs[n] = ne; }
}

// scatter edges into bucket-grouped pairs; positions via private LDS cursors (no global atomics)
__global__ __launch_bounds__(256) void scatter(const int* __restrict__ ei, const int* __restrict__ gh,
                                               const int* __restrict__ bukbase, uint* __restrict__ pairs,
                                               int ne, int nbuk) {
    __shared__ int cur[MAXBUK];
    int g = blockIdx.x;
    for (int i = threadIdx.x; i < nbuk; i += 256)
        cur[i] = bukbase[i] + gh[(size_t)g * nbuk + i];
    __syncthreads();
    int chunk = (ne + GCH - 1) / GCH;
    int e0 = g * chunk, e1 = min(ne, e0 + chunk);
    for (int e = e0 + threadIdx.x; e < e1; e += 256) {
        int r = ei[e];        // source
        int c = ei[ne + e];   // target
        int pos = atomicAdd(&cur[c >> 6], 1);
        pairs[pos] = ((uint)r << 6) | (uint)(c & 63);
    }
}

// one block per bucket: node degrees (LDS), wave scan -> offs/dis, place edges in final CSR order
__global__ __launch_bounds__(256) void csr_finalize(const uint* __restrict__ pairs, const int* __restrict__ bukbase,
                                                    int* __restrict__ offs, float* __restrict__ dis,
                                                    int* __restrict__ ebuf, int n) {
    __shared__ int cnt[64], cur2[64];
    int b = blockIdx.x;
    int t = threadIdx.x;
    int node0 = b * 64;
    if (t < 64) cnt[t] = 0;
    __syncthreads();
    int wbeg = bukbase[b], wend = bukbase[b + 1];
    for (int e = wbeg + t; e < wend; e += 256)
        atomicAdd(&cnt[pairs[e] & 63u], 1);
    __syncthreads();
    if (t < 64) {
        int c = cnt[t];
        int ps = c;
        #pragma unroll
        for (int off = 1; off < 64; off <<= 1) { int x = __shfl_up(ps, off); if (t >= off) ps += x; }
        int lo = wbeg + ps - c;   // exclusive
        int node = node0 + t;
        if (node < n) { offs[node] = lo; dis[node] = rsqrtf((float)(c + 1)); }  // deg = in-edges + self loop
        cur2[t] = lo;
    }
    __syncthreads();
    for (int e = wbeg + t; e < wend; e += 256) {
        uint p = pairs[e];
        int pos = atomicAdd(&cur2[p & 63u], 1);
        ebuf[pos] = (int)(p >> 6);
    }
}

// ---------------- small prep ----------------

__global__ void compute_u(const float* __restrict__ skip_w, const float* __restrict__ readout_w, float* u) {
    int i = blockIdx.x;
    int d = threadIdx.x;
    float s = 0.f;
    const float* sw = skip_w + i * DD * DD + d * DD;
    const float* rw = readout_w + i * DD;
    for (int j = 0; j < DD; j++) s += sw[j] * rw[j];
    u[i * DD + d] = s;
}

__global__ __launch_bounds__(256) void prep_w(const float* __restrict__ emb_w, const float* __restrict__ gcn_w,
                                              ushort* __restrict__ WTall) {
    int b = blockIdx.x;  // 0 = emb, 1..3 = gcn layer b-1
    const float* W = (b == 0) ? emb_w : gcn_w + (size_t)(b - 1) * DD * DD;
    ushort* WT = WTall + (size_t)b * DD * DD;
    for (int i = threadIdx.x; i < DD * DD; i += 256) {
        int k = i >> 7, nn = i & 127;
        WT[nn * DD + k] = f2b(W[i]);
    }
}

__global__ __launch_bounds__(256) void cvt_f2b(const float* __restrict__ in, ushort* __restrict__ outb, int n4) {
    int i = blockIdx.x * 256 + threadIdx.x;
    if (i < n4) {
        float4 v = *(const float4*)(in + (size_t)i * 4);
        ushort4 o;
        o.x = f2b(v.x); o.y = f2b(v.y); o.z = f2b(v.z); o.w = f2b(v.w);
        *(ushort4*)(outb + (size_t)i * 4) = o;
    }
}

// ---------------- MFMA GEMM: Y = ((X @ W) + bias) * scale[row], bf16 I/O ----------------
__global__ __launch_bounds__(256) void gemm_mfma(const ushort* __restrict__ X, const ushort* __restrict__ WT,
                                                 const float* __restrict__ bias, const float* __restrict__ scale,
                                                 ushort* __restrict__ Y, int nrows) {
    int wv = threadIdx.x >> 6;
    int lane = threadIdx.x & 63;
    int l15 = lane & 15;
    int kg = lane >> 4;
    int row0 = blockIdx.x * 128 + wv * 32;

    f32x4 acc[2][8];
    #pragma unroll
    for (int mt = 0; mt < 2; mt++)
        #pragma unroll
        for (int nt = 0; nt < 8; nt++) acc[mt][nt] = (f32x4){0.f, 0.f, 0.f, 0.f};

    int rA0 = min(row0 + l15, nrows - 1);
    int rA1 = min(row0 + 16 + l15, nrows - 1);
    const uint4* xa0 = (const uint4*)(X + (size_t)rA0 * DD);
    const uint4* xa1 = (const uint4*)(X + (size_t)rA1 * DD);

    #pragma unroll
    for (int ks = 0; ks < 4; ks++) {
        U16B a0, a1;
        a0.u = xa0[ks * 4 + kg];
        a1.u = xa1[ks * 4 + kg];
        #pragma unroll
        for (int nt = 0; nt < 8; nt++) {
            U16B b;
            b.u = ((const uint4*)(WT + (size_t)(nt * 16 + l15) * DD))[ks * 4 + kg];
            acc[0][nt] = __builtin_amdgcn_mfma_f32_16x16x32_bf16(a0.b, b.b, acc[0][nt], 0, 0, 0);
            acc[1][nt] = __builtin_amdgcn_mfma_f32_16x16x32_bf16(a1.b, b.b, acc[1][nt], 0, 0, 0);
        }
    }

    #pragma unroll
    for (int mt = 0; mt < 2; mt++) {
        #pragma unroll
        for (int r = 0; r < 4; r++) {
            int row = row0 + mt * 16 + kg * 4 + r;
            if (row < nrows) {
                float s = scale ? scale[row] : 1.f;
                #pragma unroll
                for (int nt = 0; nt < 8; nt++) {
                    int col = nt * 16 + l15;
                    float v = acc[mt][nt][r];
                    if (bias) v += bias[col];
                    Y[(size_t)row * DD + col] = f2b(v * s);
                }
            }
        }
    }
}

// ---------------- aggregation: one wave per node, 2-edge unroll ----------------
__global__ __launch_bounds__(256) void aggregate(const ushort* __restrict__ hl2, const int* __restrict__ ebuf,
                                                 const int* __restrict__ offs, const float* __restrict__ dis,
                                                 float* __restrict__ agg, int n) {
    int w = threadIdx.x >> 6;
    int lane = threadIdx.x & 63;
    int v = blockIdx.x * 4 + w;
    if (v >= n) return;
    uint self = ((const uint*)(hl2 + (size_t)v * DD))[lane];
    float ax = __uint_as_float(self << 16);
    float ay = __uint_as_float(self & 0xffff0000u);
    float bx = 0.f, by = 0.f;
    int e0 = offs[v], e1 = offs[v + 1];
    int e = e0;
    for (; e + 1 < e1; e += 2) {
        int s0 = ebuf[e], s1 = ebuf[e + 1];
        uint m0 = ((const uint*)(hl2 + (size_t)s0 * DD))[lane];
        uint m1 = ((const uint*)(hl2 + (size_t)s1 * DD))[lane];
        ax += __uint_as_float(m0 << 16);
        ay += __uint_as_float(m0 & 0xffff0000u);
        bx += __uint_as_float(m1 << 16);
        by += __uint_as_float(m1 & 0xffff0000u);
    }
    if (e < e1) {
        uint m = ((const uint*)(hl2 + (size_t)ebuf[e] * DD))[lane];
        ax += __uint_as_float(m << 16);
        ay += __uint_as_float(m & 0xffff0000u);
    }
    float dv = dis[v];
    float2 o; o.x = (ax + bx) * dv; o.y = (ay + by) * dv;
    ((float2*)(agg + (size_t)v * DD))[lane] = o;
}

// ---------------- batchnorm ----------------

__global__ void zero_stats(float* stats) { stats[threadIdx.x] = 0.f; }

__global__ __launch_bounds__(1024) void bn_stats(const float* __restrict__ agg, float* stats, int n) {
    int d = threadIdx.x & 127;
    int rg = threadIdx.x >> 7;   // 0..7
    float s = 0.f, s2 = 0.f;
    for (int i = blockIdx.x * 8 + rg; i < n; i += gridDim.x * 8) {
        float v = agg[(size_t)i * DD + d];
        s += v; s2 += v * v;
    }
    __shared__ float ls[8][DD], ls2[8][DD];
    ls[rg][d] = s; ls2[rg][d] = s2;
    __syncthreads();
    if (rg == 0) {
        float a = 0.f, a2 = 0.f;
        #pragma unroll
        for (int r = 0; r < 8; r++) { a += ls[r][d]; a2 += ls2[r][d]; }
        atomicAdd(&stats[d], a);
        atomicAdd(&stats[d + DD], a2);
    }
}

__global__ __launch_bounds__(256) void bn_apply(const float* __restrict__ agg, const float* __restrict__ stats,
                                                const float* __restrict__ g, const float* __restrict__ b,
                                                const float* __restrict__ u, ushort* __restrict__ fout,
                                                float* __restrict__ logits, int n, float invN) {
    int d = threadIdx.x & 127;
    int which = threadIdx.x >> 7;
    int i = blockIdx.x * 2 + which;
    __shared__ float red[2][2];
    float c = 0.f;
    if (i < n) {
        float mean = stats[d] * invN;
        float ex2 = stats[d + DD] * invN;
        float var = ex2 - mean * mean;
        float f = (agg[(size_t)i * DD + d] - mean) * rsqrtf(var + EPS) * g[d] + b[d];
        f = fmaxf(f, 0.f);
        fout[(size_t)i * DD + d] = f2b(f);
        c = f * u[d];
    }
    #pragma unroll
    for (int off = 32; off; off >>= 1) c += __shfl_down(c, off);
    int lane = threadIdx.x & 63;
    int wv = (threadIdx.x >> 6) & 1;
    if (lane == 0) red[which][wv] = c;
    __syncthreads();
    if (i < n && (threadIdx.x & 127) == 0) logits[i] += red[which][0] + red[which][1];
}

__global__ __launch_bounds__(256) void dot_init(const ushort* __restrict__ h, const float* __restrict__ u,
                                                float* __restrict__ logits, int n) {
    int d = threadIdx.x & 127;
    int which = threadIdx.x >> 7;
    int i = blockIdx.x * 2 + which;
    __shared__ float red[2][2];
    float c = 0.f;
    if (i < n) c = b2f(h[(size_t)i * DD + d]) * u[d];
    #pragma unroll
    for (int off = 32; off; off >>= 1) c += __shfl_down(c, off);
    int lane = threadIdx.x & 63;
    int wv = (threadIdx.x >> 6) & 1;
    if (lane == 0) red[which][wv] = c;
    __syncthreads();
    if (i < n && (threadIdx.x & 127) == 0) logits[i] = red[which][0] + red[which][1];
}

__global__ __launch_bounds__(256) void finalize(const float* __restrict__ logits, float* __restrict__ out, int n) {
    int i = blockIdx.x * 256 + threadIdx.x;
    if (i < n) {
        float x = logits[i];
        out[i] = x;
        out[n + i] = 1.f / (1.f + expf(-x));
    }
}

// ---------------- host ----------------

static inline size_t align_up(size_t x, size_t a) { return (x + a - 1) & ~(a - 1); }

extern "C" void kernel_launch(void* const* d_in, const int* in_sizes, int n_in,
                              void* d_out, int out_size, void* d_ws, size_t ws_size,
                              hipStream_t stream) {
    const float* x       = (const float*)d_in[0];
    const int*   ei      = (const int*)d_in[1];
    const float* emb_w   = (const float*)d_in[2];
    const float* emb_b   = (const float*)d_in[3];
    const float* gcn_w   = (const float*)d_in[4];
    // d_in[5] = gcn_b: no-op (constant shift immediately normalized away by BatchNorm)
    const float* bn_g    = (const float*)d_in[6];
    const float* bn_b    = (const float*)d_in[7];
    const float* skip_w  = (const float*)d_in[8];
    const float* readout = (const float*)d_in[9];
    float* out = (float*)d_out;

    const int N = in_sizes[0] / DD;
    const int E = in_sizes[1] / 2;
    const int NBUK = (N + 63) / 64;   // must be <= MAXBUK

    char* p = (char*)d_ws;
    size_t off = 0;
    auto alloc = [&](size_t bytes) { void* r = p + off; off = align_up(off + bytes, 256); return r; };
    float*  dis     = (float*) alloc((size_t)N * 4);
    int*    offs    = (int*)   alloc((size_t)(N + 1) * 4);
    int*    ebuf    = (int*)   alloc((size_t)E * 4);
    uint*   pairs   = (uint*)  alloc((size_t)E * 4);
    int*    gh      = (int*)   alloc((size_t)GCH * NBUK * 4);
    int*    total   = (int*)   alloc((size_t)NBUK * 4);
    int*    bukbase = (int*)   alloc((size_t)(NBUK + 1) * 4);
    float*  u       = (float*) alloc(4 * DD * 4);
    float*  stats   = (float*) alloc(2 * DD * 4);
    ushort* WTall   = (ushort*)alloc(4 * (size_t)DD * DD * 2);
    float*  logits  = (float*) alloc((size_t)N * 4);
    ushort* featsB  = (ushort*)alloc((size_t)N * DD * 2);
    ushort* hl2B    = (ushort*)alloc((size_t)N * DD * 2);
    float*  aggF    = (float*) alloc((size_t)N * DD * 4);
    ushort* xB      = (ushort*)aggF;   // alias: xB dead before aggF first written
    (void)ws_size;

    int gN = (N + 255) / 256;
    int gG = (N + 127) / 128;

    // CSR build (contention-free counting sort)
    count_hist<<<GCH, 256, 0, stream>>>(ei, gh, E, NBUK);
    colscan<<<(NBUK + 3) / 4, 256, 0, stream>>>(gh, total, NBUK);
    bukscan<<<1, 1024, 0, stream>>>(total, bukbase, offs, NBUK, N, E);
    scatter<<<GCH, 256, 0, stream>>>(ei, gh, bukbase, pairs, E, NBUK);
    csr_finalize<<<NBUK, 256, 0, stream>>>(pairs, bukbase, offs, dis, ebuf, N);

    compute_u<<<4, DD, 0, stream>>>(skip_w, readout, u);
    prep_w<<<4, 256, 0, stream>>>(emb_w, gcn_w, WTall);
    cvt_f2b<<<(N * DD / 4 + 255) / 256, 256, 0, stream>>>(x, xB, N * DD / 4);

    gemm_mfma<<<gG, 256, 0, stream>>>(xB, WTall, emb_b, nullptr, featsB, N);
    dot_init<<<(N + 1) / 2, 256, 0, stream>>>(featsB, u, logits, N);

    for (int l = 0; l < 3; l++) {  // layer 3's output is dead (skip uses feats[0..3])
        gemm_mfma<<<gG, 256, 0, stream>>>(featsB, WTall + (size_t)(l + 1) * DD * DD, nullptr, dis, hl2B, N);
        aggregate<<<(N + 3) / 4, 256, 0, stream>>>(hl2B, ebuf, offs, dis, aggF, N);
        zero_stats<<<1, 2 * DD, 0, stream>>>(stats);
        bn_stats<<<256, 1024, 0, stream>>>(aggF, stats, N);
        bn_apply<<<(N + 1) / 2, 256, 0, stream>>>(aggF, stats, bn_g + l * DD, bn_b + l * DD,
                                                  u + (l + 1) * DD, featsB, logits, N, 1.0f / N);
    }
    finalize<<<gN, 256, 0, stream>>>(logits, out, N);
}

// Round 7
// 525.876 us; speedup vs baseline: 2.7750x; 1.3102x over previous
//
#include <hip/hip_runtime.h>
#include <hip/hip_bf16.h>
#include <math.h>

#define DD 128
#define EPS 1e-5f
#define GCH 512      // histogram/scatter chunks (must equal scatter grid)
#define MAXBUK 1600  // >= ceil(N/64); N=100000 -> 1563

using bf16x8 = __attribute__((ext_vector_type(8))) __bf16;
using f32x4  = __attribute__((ext_vector_type(4))) float;
union U16B { uint4 u; bf16x8 b; ushort s[8]; };

__device__ inline ushort f2b(float f) {
    uint u = __float_as_uint(f);
    return (ushort)((u + 0x7fffu + ((u >> 16) & 1u)) >> 16);
}
__device__ inline float b2f(ushort h) { return __uint_as_float(((uint)h) << 16); }
__device__ inline float blo(uint m) { return __uint_as_float(m << 16); }
__device__ inline float bhi(uint m) { return __uint_as_float(m & 0xffff0000u); }

// ---------------- CSR build: contention-free counting sort ----------------

__global__ __launch_bounds__(256) void count_hist(const int* __restrict__ ei, int* __restrict__ gh,
                                                  int ne, int nbuk) {
    __shared__ int hist[MAXBUK];
    for (int i = threadIdx.x; i < nbuk; i += 256) hist[i] = 0;
    __syncthreads();
    int chunk = (ne + GCH - 1) / GCH;
    int e0 = blockIdx.x * chunk, e1 = min(ne, e0 + chunk);
    for (int e = e0 + threadIdx.x; e < e1; e += 256)
        atomicAdd(&hist[ei[ne + e] >> 6], 1);
    __syncthreads();
    for (int i = threadIdx.x; i < nbuk; i += 256)
        gh[(size_t)blockIdx.x * nbuk + i] = hist[i];
}

__global__ __launch_bounds__(256) void colscan(int* __restrict__ gh, int* __restrict__ total, int nbuk) {
    int k = blockIdx.x * 4 + (threadIdx.x >> 6);
    int lane = threadIdx.x & 63;
    if (k >= nbuk) return;
    const int PER = GCH / 64;  // 8
    int v[PER]; int s = 0;
    #pragma unroll
    for (int j = 0; j < PER; j++) { v[j] = gh[(size_t)(PER * lane + j) * nbuk + k]; s += v[j]; }
    int ps = s;
    #pragma unroll
    for (int off = 1; off < 64; off <<= 1) { int t = __shfl_up(ps, off); if (lane >= off) ps += t; }
    int run = ps - s;
    #pragma unroll
    for (int j = 0; j < PER; j++) { gh[(size_t)(PER * lane + j) * nbuk + k] = run; run += v[j]; }
    if (lane == 63) total[k] = run;
}

__global__ __launch_bounds__(1024) void bukscan(const int* __restrict__ total, int* __restrict__ bukbase,
                                                int* __restrict__ offs, int nbuk, int n, int ne) {
    __shared__ int sm[2048];
    int t = threadIdx.x;
    sm[t] = (t < nbuk) ? total[t] : 0;
    sm[t + 1024] = (t + 1024 < nbuk) ? total[t + 1024] : 0;
    __syncthreads();
    for (int off = 1; off < 2048; off <<= 1) {
        int a = sm[t],        b = (t >= off) ? sm[t - off] : 0;
        int a2 = sm[t + 1024], b2 = (t + 1024 >= off) ? sm[t + 1024 - off] : 0;
        __syncthreads();
        sm[t] = a + b; sm[t + 1024] = a2 + b2;
        __syncthreads();
    }
    if (t < nbuk) bukbase[t] = (t == 0) ? 0 : sm[t - 1];
    int u2 = t + 1024;
    if (u2 < nbuk) bukbase[u2] = sm[u2 - 1];
    if (t == 0) { bukbase[nbuk] = sm[nbuk - 1]; offs[n] = ne; }
}

__global__ __launch_bounds__(256) void scatter(const int* __restrict__ ei, const int* __restrict__ gh,
                                               const int* __restrict__ bukbase, uint* __restrict__ pairs,
                                               int ne, int nbuk) {
    __shared__ int cur[MAXBUK];
    int g = blockIdx.x;
    for (int i = threadIdx.x; i < nbuk; i += 256)
        cur[i] = bukbase[i] + gh[(size_t)g * nbuk + i];
    __syncthreads();
    int chunk = (ne + GCH - 1) / GCH;
    int e0 = g * chunk, e1 = min(ne, e0 + chunk);
    for (int e = e0 + threadIdx.x; e < e1; e += 256) {
        int r = ei[e];
        int c = ei[ne + e];
        int pos = atomicAdd(&cur[c >> 6], 1);
        pairs[pos] = ((uint)r << 6) | (uint)(c & 63);
    }
}

__global__ __launch_bounds__(256) void csr_finalize(const uint* __restrict__ pairs, const int* __restrict__ bukbase,
                                                    int* __restrict__ offs, float* __restrict__ dis,
                                                    int* __restrict__ ebuf, int n) {
    __shared__ int cnt[64], cur2[64];
    int b = blockIdx.x;
    int t = threadIdx.x;
    int node0 = b * 64;
    if (t < 64) cnt[t] = 0;
    __syncthreads();
    int wbeg = bukbase[b], wend = bukbase[b + 1];
    for (int e = wbeg + t; e < wend; e += 256)
        atomicAdd(&cnt[pairs[e] & 63u], 1);
    __syncthreads();
    if (t < 64) {
        int c = cnt[t];
        int ps = c;
        #pragma unroll
        for (int off = 1; off < 64; off <<= 1) { int x = __shfl_up(ps, off); if (t >= off) ps += x; }
        int lo = wbeg + ps - c;
        int node = node0 + t;
        if (node < n) { offs[node] = lo; dis[node] = rsqrtf((float)(c + 1)); }
        cur2[t] = lo;
    }
    __syncthreads();
    for (int e = wbeg + t; e < wend; e += 256) {
        uint p = pairs[e];
        int pos = atomicAdd(&cur2[p & 63u], 1);
        ebuf[pos] = (int)(p >> 6);
    }
}

// ---------------- small prep ----------------

__global__ void compute_u(const float* __restrict__ skip_w, const float* __restrict__ readout_w, float* u) {
    int i = blockIdx.x;
    int d = threadIdx.x;
    float s = 0.f;
    const float* sw = skip_w + i * DD * DD + d * DD;
    const float* rw = readout_w + i * DD;
    for (int j = 0; j < DD; j++) s += sw[j] * rw[j];
    u[i * DD + d] = s;
}

__global__ __launch_bounds__(256) void prep_w(const float* __restrict__ emb_w, const float* __restrict__ gcn_w,
                                              ushort* __restrict__ WTall) {
    int b = blockIdx.x;  // 0 = emb, 1..3 = gcn layer b-1
    const float* W = (b == 0) ? emb_w : gcn_w + (size_t)(b - 1) * DD * DD;
    ushort* WT = WTall + (size_t)b * DD * DD;
    for (int i = threadIdx.x; i < DD * DD; i += 256) {
        int k = i >> 7, nn = i & 127;
        WT[nn * DD + k] = f2b(W[i]);
    }
}

__global__ void zero_arr(float* a, int n) {
    int i = blockIdx.x * blockDim.x + threadIdx.x;
    if (i < n) a[i] = 0.f;
}

// ---------------- fused MFMA GEMM ----------------
// Y = (( BNrelu?(X) @ W ) + bias) * scale[row];  optionally logits[row] {=, +=} BNrelu?(X[row]) . uvec
// BNrelu applied when stats != null (coefs from stats/bng/bnb); X fp32 when xf32 (embedding).
__global__ __launch_bounds__(256) void gemm_fused(
    const void* __restrict__ Xv, int xf32,
    const ushort* __restrict__ WT,
    const float* __restrict__ bias, const float* __restrict__ scale,
    const float* __restrict__ stats, const float* __restrict__ bng, const float* __restrict__ bnb, float invN,
    const float* __restrict__ uvec, float* __restrict__ logits, int dot_init_mode,
    ushort* __restrict__ Y, int nrows)
{
    __shared__ float As[DD], Bs[DD], Us[DD];
    int t = threadIdx.x;
    bool has_bn = (stats != nullptr);
    bool has_u  = (uvec != nullptr);
    if (has_bn && t < DD) {
        float mean = stats[t] * invN;
        float var = stats[DD + t] * invN - mean * mean;
        float a = bng[t] * rsqrtf(var + EPS);
        As[t] = a; Bs[t] = bnb[t] - mean * a;
    }
    if (has_u && t < DD) Us[t] = uvec[t];
    if (has_bn || has_u) __syncthreads();

    int wv = t >> 6;
    int lane = t & 63;
    int l15 = lane & 15;
    int kg = lane >> 4;
    int row0 = blockIdx.x * 128 + wv * 32;

    f32x4 acc[2][8];
    #pragma unroll
    for (int mt = 0; mt < 2; mt++)
        #pragma unroll
        for (int nt = 0; nt < 8; nt++) acc[mt][nt] = (f32x4){0.f, 0.f, 0.f, 0.f};

    int rA0 = min(row0 + l15, nrows - 1);
    int rA1 = min(row0 + 16 + l15, nrows - 1);
    float dot0 = 0.f, dot1 = 0.f;

    #pragma unroll
    for (int ks = 0; ks < 4; ks++) {
        U16B a0, a1;
        int d0 = ks * 32 + kg * 8;
        if (xf32) {
            const float* x0 = (const float*)Xv + (size_t)rA0 * DD + d0;
            const float* x1 = (const float*)Xv + (size_t)rA1 * DD + d0;
            float4 p0 = *(const float4*)x0, q0 = *(const float4*)(x0 + 4);
            float4 p1 = *(const float4*)x1, q1 = *(const float4*)(x1 + 4);
            a0.s[0]=f2b(p0.x); a0.s[1]=f2b(p0.y); a0.s[2]=f2b(p0.z); a0.s[3]=f2b(p0.w);
            a0.s[4]=f2b(q0.x); a0.s[5]=f2b(q0.y); a0.s[6]=f2b(q0.z); a0.s[7]=f2b(q0.w);
            a1.s[0]=f2b(p1.x); a1.s[1]=f2b(p1.y); a1.s[2]=f2b(p1.z); a1.s[3]=f2b(p1.w);
            a1.s[4]=f2b(q1.x); a1.s[5]=f2b(q1.y); a1.s[6]=f2b(q1.z); a1.s[7]=f2b(q1.w);
        } else {
            const ushort* X = (const ushort*)Xv;
            a0.u = ((const uint4*)(X + (size_t)rA0 * DD))[ks * 4 + kg];
            a1.u = ((const uint4*)(X + (size_t)rA1 * DD))[ks * 4 + kg];
            if (has_bn || has_u) {
                #pragma unroll
                for (int j = 0; j < 8; j++) {
                    float v0 = b2f(a0.s[j]);
                    float v1 = b2f(a1.s[j]);
                    if (has_bn) {
                        float A = As[d0 + j], B = Bs[d0 + j];
                        v0 = fmaxf(fmaf(A, v0, B), 0.f);
                        v1 = fmaxf(fmaf(A, v1, B), 0.f);
                        a0.s[j] = f2b(v0); a1.s[j] = f2b(v1);
                    }
                    if (has_u) {
                        float uu = Us[d0 + j];
                        dot0 = fmaf(v0, uu, dot0);
                        dot1 = fmaf(v1, uu, dot1);
                    }
                }
            }
        }
        #pragma unroll
        for (int nt = 0; nt < 8; nt++) {
            U16B b;
            b.u = ((const uint4*)(WT + (size_t)(nt * 16 + l15) * DD))[ks * 4 + kg];
            acc[0][nt] = __builtin_amdgcn_mfma_f32_16x16x32_bf16(a0.b, b.b, acc[0][nt], 0, 0, 0);
            acc[1][nt] = __builtin_amdgcn_mfma_f32_16x16x32_bf16(a1.b, b.b, acc[1][nt], 0, 0, 0);
        }
    }

    if (has_u) {
        dot0 += __shfl_xor(dot0, 16); dot0 += __shfl_xor(dot0, 32);
        dot1 += __shfl_xor(dot1, 16); dot1 += __shfl_xor(dot1, 32);
        if (kg == 0) {
            int r0 = row0 + l15, r1 = row0 + 16 + l15;
            if (r0 < nrows) logits[r0] = dot_init_mode ? dot0 : (logits[r0] + dot0);
            if (r1 < nrows) logits[r1] = dot_init_mode ? dot1 : (logits[r1] + dot1);
        }
    }

    #pragma unroll
    for (int mt = 0; mt < 2; mt++) {
        #pragma unroll
        for (int r = 0; r < 4; r++) {
            int row = row0 + mt * 16 + kg * 4 + r;
            if (row < nrows) {
                float s = scale ? scale[row] : 1.f;
                #pragma unroll
                for (int nt = 0; nt < 8; nt++) {
                    int col = nt * 16 + l15;
                    float v = acc[mt][nt][r];
                    if (bias) v += bias[col];
                    Y[(size_t)row * DD + col] = f2b(v * s);
                }
            }
        }
    }
}

// ---------------- aggregation: one wave per node, 4-edge unroll, bf16 out ----------------
__global__ __launch_bounds__(256) void aggregate(const ushort* __restrict__ hl2, const int* __restrict__ ebuf,
                                                 const int* __restrict__ offs, const float* __restrict__ dis,
                                                 ushort* __restrict__ aggb, int n) {
    int w = threadIdx.x >> 6;
    int lane = threadIdx.x & 63;
    int v = blockIdx.x * 4 + w;
    if (v >= n) return;
    const uint* base = (const uint*)hl2;
    uint self = base[(size_t)v * 64 + lane];
    float ax = blo(self), ay = bhi(self);
    float bx = 0.f, by = 0.f, cx = 0.f, cy = 0.f, dx = 0.f, dy = 0.f;
    int e0 = offs[v], e1 = offs[v + 1];
    int e = e0;
    for (; e + 3 < e1; e += 4) {
        int s0 = ebuf[e], s1 = ebuf[e + 1], s2 = ebuf[e + 2], s3 = ebuf[e + 3];
        uint m0 = base[(size_t)s0 * 64 + lane];
        uint m1 = base[(size_t)s1 * 64 + lane];
        uint m2 = base[(size_t)s2 * 64 + lane];
        uint m3 = base[(size_t)s3 * 64 + lane];
        ax += blo(m0); ay += bhi(m0);
        bx += blo(m1); by += bhi(m1);
        cx += blo(m2); cy += bhi(m2);
        dx += blo(m3); dy += bhi(m3);
    }
    for (; e < e1; e++) {
        uint m = base[(size_t)ebuf[e] * 64 + lane];
        ax += blo(m); ay += bhi(m);
    }
    float dv = dis[v];
    float ox = (ax + bx + cx + dx) * dv;
    float oy = (ay + by + cy + dy) * dv;
    ((uint*)aggb)[(size_t)v * 64 + lane] = ((uint)f2b(oy) << 16) | (uint)f2b(ox);
}

// ---------------- batchnorm stats (bf16 input, fp32 accum) ----------------
__global__ __launch_bounds__(1024) void bn_stats_b(const ushort* __restrict__ aggb, float* stats, int n) {
    int lane = threadIdx.x & 63;
    int rg = threadIdx.x >> 6;  // 0..15
    float sx = 0.f, sy = 0.f, qx = 0.f, qy = 0.f;
    for (int i = blockIdx.x * 16 + rg; i < n; i += gridDim.x * 16) {
        uint m = ((const uint*)aggb)[(size_t)i * 64 + lane];
        float vx = blo(m), vy = bhi(m);
        sx += vx; sy += vy; qx += vx * vx; qy += vy * vy;
    }
    __shared__ float4 red[16][64];
    red[rg][lane] = make_float4(sx, sy, qx, qy);
    __syncthreads();
    if (rg == 0) {
        float4 a = red[0][lane];
        #pragma unroll
        for (int r = 1; r < 16; r++) {
            float4 x2 = red[r][lane];
            a.x += x2.x; a.y += x2.y; a.z += x2.z; a.w += x2.w;
        }
        atomicAdd(&stats[2 * lane], a.x);
        atomicAdd(&stats[2 * lane + 1], a.y);
        atomicAdd(&stats[DD + 2 * lane], a.z);
        atomicAdd(&stats[DD + 2 * lane + 1], a.w);
    }
}

// ---------------- last layer: BN+relu+dot only ----------------
__global__ __launch_bounds__(256) void bn_dot(const ushort* __restrict__ aggb, const float* __restrict__ stats,
                                              const float* __restrict__ g, const float* __restrict__ b,
                                              const float* __restrict__ uvec, float* __restrict__ logits,
                                              int n, float invN) {
    __shared__ float As[DD], Bs[DD], Us[DD];
    int t = threadIdx.x;
    if (t < DD) {
        float mean = stats[t] * invN;
        float var = stats[DD + t] * invN - mean * mean;
        float a = g[t] * rsqrtf(var + EPS);
        As[t] = a; Bs[t] = b[t] - mean * a; Us[t] = uvec[t];
    }
    __syncthreads();
    int w = t >> 6, lane = t & 63;
    int v = blockIdx.x * 4 + w;
    if (v >= n) return;
    uint m = ((const uint*)aggb)[(size_t)v * 64 + lane];
    int d0 = 2 * lane;
    float f0 = fmaxf(fmaf(As[d0], blo(m), Bs[d0]), 0.f);
    float f1 = fmaxf(fmaf(As[d0 + 1], bhi(m), Bs[d0 + 1]), 0.f);
    float c = f0 * Us[d0] + f1 * Us[d0 + 1];
    #pragma unroll
    for (int off = 32; off; off >>= 1) c += __shfl_down(c, off);
    if (lane == 0) logits[v] += c;
}

__global__ __launch_bounds__(256) void finalize(const float* __restrict__ logits, float* __restrict__ out, int n) {
    int i = blockIdx.x * 256 + threadIdx.x;
    if (i < n) {
        float x = logits[i];
        out[i] = x;
        out[n + i] = 1.f / (1.f + expf(-x));
    }
}

// ---------------- host ----------------

static inline size_t align_up(size_t x, size_t a) { return (x + a - 1) & ~(a - 1); }

extern "C" void kernel_launch(void* const* d_in, const int* in_sizes, int n_in,
                              void* d_out, int out_size, void* d_ws, size_t ws_size,
                              hipStream_t stream) {
    const float* x       = (const float*)d_in[0];
    const int*   ei      = (const int*)d_in[1];
    const float* emb_w   = (const float*)d_in[2];
    const float* emb_b   = (const float*)d_in[3];
    const float* gcn_w   = (const float*)d_in[4];
    // d_in[5] = gcn_b: no-op (constant shift immediately normalized away by BatchNorm)
    const float* bn_g    = (const float*)d_in[6];
    const float* bn_b    = (const float*)d_in[7];
    const float* skip_w  = (const float*)d_in[8];
    const float* readout = (const float*)d_in[9];
    float* out = (float*)d_out;

    const int N = in_sizes[0] / DD;
    const int E = in_sizes[1] / 2;
    const int NBUK = (N + 63) / 64;
    const float invN = 1.0f / N;

    char* p = (char*)d_ws;
    size_t off = 0;
    auto alloc = [&](size_t bytes) { void* r = p + off; off = align_up(off + bytes, 256); return r; };
    float*  dis     = (float*) alloc((size_t)N * 4);
    int*    offs    = (int*)   alloc((size_t)(N + 1) * 4);
    int*    ebuf    = (int*)   alloc((size_t)E * 4);
    uint*   pairs   = (uint*)  alloc((size_t)E * 4);
    int*    gh      = (int*)   alloc((size_t)GCH * NBUK * 4);
    int*    total   = (int*)   alloc((size_t)NBUK * 4);
    int*    bukbase = (int*)   alloc((size_t)(NBUK + 1) * 4);
    float*  u       = (float*) alloc(4 * DD * 4);
    float*  stats   = (float*) alloc(3 * 2 * DD * 4);
    ushort* WTall   = (ushort*)alloc(4 * (size_t)DD * DD * 2);
    float*  logits  = (float*) alloc((size_t)N * 4);
    ushort* hB      = (ushort*)alloc((size_t)N * DD * 2);   // embedding out
    ushort* hl2B    = (ushort*)alloc((size_t)N * DD * 2);   // gemm out (scaled)
    ushort* aggB    = (ushort*)alloc((size_t)N * DD * 2);   // aggregation out
    (void)ws_size;

    int gN = (N + 255) / 256;
    int gG = (N + 127) / 128;

    // CSR build (contention-free counting sort)
    count_hist<<<GCH, 256, 0, stream>>>(ei, gh, E, NBUK);
    colscan<<<(NBUK + 3) / 4, 256, 0, stream>>>(gh, total, NBUK);
    bukscan<<<1, 1024, 0, stream>>>(total, bukbase, offs, NBUK, N, E);
    scatter<<<GCH, 256, 0, stream>>>(ei, gh, bukbase, pairs, E, NBUK);
    csr_finalize<<<NBUK, 256, 0, stream>>>(pairs, bukbase, offs, dis, ebuf, N);

    compute_u<<<4, DD, 0, stream>>>(skip_w, readout, u);
    prep_w<<<4, 256, 0, stream>>>(emb_w, gcn_w, WTall);
    zero_arr<<<1, 768, 0, stream>>>(stats, 3 * 2 * DD);

    // embedding: h = x @ emb_w + emb_b  (reads fp32 x directly)
    gemm_fused<<<gG, 256, 0, stream>>>(x, 1, WTall, emb_b, nullptr,
                                       nullptr, nullptr, nullptr, invN,
                                       nullptr, nullptr, 0, hB, N);

    for (int l = 0; l < 3; l++) {  // layer 3's output is dead (skip uses feats[0..3])
        // in: feats[l]; BN fuse for l>0 (stats of layer l-1); dot feats[l].u[l]; out hl2 = (f @ W_l)*dis
        const ushort* Xin = (l == 0) ? hB : aggB;
        const float* st   = (l == 0) ? nullptr : stats + (size_t)(l - 1) * 2 * DD;
        const float* g    = (l == 0) ? nullptr : bn_g + (size_t)(l - 1) * DD;
        const float* bb   = (l == 0) ? nullptr : bn_b + (size_t)(l - 1) * DD;
        gemm_fused<<<gG, 256, 0, stream>>>(Xin, 0, WTall + (size_t)(l + 1) * DD * DD, nullptr, dis,
                                           st, g, bb, invN,
                                           u + (size_t)l * DD, logits, (l == 0) ? 1 : 0, hl2B, N);
        aggregate<<<(N + 3) / 4, 256, 0, stream>>>(hl2B, ebuf, offs, dis, aggB, N);
        bn_stats_b<<<256, 1024, 0, stream>>>(aggB, stats + (size_t)l * 2 * DD, N);
    }
    // feats[3] = BNrelu(agg_2): logits += feats[3] . u[3]
    bn_dot<<<(N + 3) / 4, 256, 0, stream>>>(aggB, stats + 2 * 2 * DD, bn_g + 2 * DD, bn_b + 2 * DD,
                                            u + 3 * DD, logits, N, invN);
    finalize<<<gN, 256, 0, stream>>>(logits, out, N);
}